// Round 3
// baseline (8292279.688 us; speedup 1.0000x reference)
//
#include <hip/hip_runtime.h>
#include <math.h>

static constexpr int F     = 64;
static constexpr int GRIDV = 64;
static constexpr int SEG   = 16 * GRIDV * GRIDV;   // 65536 clusters
static constexpr int MINB  = 1024;                 // blocks for k_min
static constexpr int GPART = 512;                  // blocks for edge hist/partition
static constexpr int TBL   = 256 * GPART;          // coarse table entries (131072)
static constexpr int SORTP = 16384;                // bitonic capacity per coarse bin

__device__ __forceinline__ float wave_min(float v) {
    for (int o = 32; o > 0; o >>= 1) v = fminf(v, __shfl_down(v, o));
    return v;
}
__device__ __forceinline__ float wave_max(float v) {
    for (int o = 32; o > 0; o >>= 1) v = fmaxf(v, __shfl_down(v, o));
    return v;
}

// ---- zero counters ----
__global__ void k_init(unsigned* cnts, int ncnt) {
    int i = blockIdx.x * blockDim.x + threadIdx.x;
    int stride = gridDim.x * blockDim.x;
    for (int j = i; j < ncnt; j += stride) cnts[j] = 0u;
}

// ---- per-block partial min of pos ----
__global__ void k_min(const float2* __restrict__ pos, int n, float2* __restrict__ pmin) {
    __shared__ float shx[4], shy[4];
    int stride = gridDim.x * blockDim.x;
    float mx = INFINITY, my = INFINITY;
    for (int i = blockIdx.x * blockDim.x + threadIdx.x; i < n; i += stride) {
        float2 p = pos[i];
        mx = fminf(mx, p.x); my = fminf(my, p.y);
    }
    mx = wave_min(mx); my = wave_min(my);
    int w = threadIdx.x >> 6;
    if ((threadIdx.x & 63) == 0) { shx[w] = mx; shy[w] = my; }
    __syncthreads();
    if (threadIdx.x == 0) {
        mx = fminf(fminf(shx[0], shx[1]), fminf(shx[2], shx[3]));
        my = fminf(fminf(shy[0], shy[1]), fminf(shy[2], shy[3]));
        pmin[blockIdx.x] = make_float2(mx, my);
    }
}

__global__ void k_minred(const float2* __restrict__ pmin, int nb, unsigned* hdr) {
    __shared__ float shx[16], shy[16];
    int t = threadIdx.x;
    float mx = INFINITY, my = INFINITY;
    for (int i = t; i < nb; i += blockDim.x) {
        float2 p = pmin[i];
        mx = fminf(mx, p.x); my = fminf(my, p.y);
    }
    mx = wave_min(mx); my = wave_min(my);
    int w = t >> 6;
    if ((t & 63) == 0) { shx[w] = mx; shy[w] = my; }
    __syncthreads();
    if (t == 0) {
        int nw = (blockDim.x + 63) >> 6;
        for (int i = 1; i < nw; ++i) { mx = fminf(mx, shx[i]); my = fminf(my, shy[i]); }
        hdr[0] = (unsigned)__float_as_int(mx);
        hdr[1] = (unsigned)__float_as_int(my);
    }
}

// ---- per-node cluster id + node histogram ----
__global__ void k_cluster(const float2* __restrict__ pos, const int* __restrict__ batch, int n,
                          const unsigned* __restrict__ hdr, int* __restrict__ cl,
                          unsigned* __restrict__ node_cnt) {
    int i = blockIdx.x * blockDim.x + threadIdx.x;
    if (i >= n) return;
    float sx = __int_as_float((int)hdr[0]);
    float sy = __int_as_float((int)hdr[1]);
    float2 p = pos[i];
    int vx = (int)floorf((p.x - sx) * 64.0f);   // /VOXEL_SIZE == *64 exactly
    int vy = (int)floorf((p.y - sy) * 64.0f);
    vx = min(max(vx, 0), GRIDV - 1);
    vy = min(max(vy, 0), GRIDV - 1);
    int c = batch[i] * (GRIDV * GRIDV) + vy * GRIDV + vx;
    cl[i] = c;
    atomicAdd(&node_cnt[c], 1u);
}

// ---- hierarchical exclusive scan (n entries, n = gridDim*1024) ----
__global__ void k_scan1(const unsigned* __restrict__ cnt, unsigned* __restrict__ off,
                        unsigned* __restrict__ blksum) {
    __shared__ unsigned sh[1024];
    int t = threadIdx.x;
    int g = blockIdx.x * 1024 + t;
    unsigned v = cnt[g];
    sh[t] = v;
    __syncthreads();
    for (int s = 1; s < 1024; s <<= 1) {
        unsigned u = (t >= s) ? sh[t - s] : 0u;
        __syncthreads();
        sh[t] += u;
        __syncthreads();
    }
    off[g] = sh[t] - v;
    if (t == 1023) blksum[blockIdx.x] = sh[1023];
}

// stage 2: add block bases; supports up to 128 stage-1 blocks
__global__ void k_scan_add(unsigned* __restrict__ off, const unsigned* __restrict__ blksum,
                           int n, unsigned total) {
    __shared__ unsigned sh[128];
    __shared__ unsigned base_sh;
    int t = threadIdx.x, b = blockIdx.x;
    if (t < 128) sh[t] = (t < b) ? blksum[t] : 0u;
    __syncthreads();
    if (t == 0) {
        unsigned s = 0;
        for (int i = 0; i < b; ++i) s += sh[i];
        base_sh = s;
    }
    __syncthreads();
    off[b * 1024 + t] += base_sh;
    if (b == 0 && t == 0) off[n] = total;
}

// ---- scatter nodes into cluster-sorted order (unstable) ----
__global__ void k_scatter_nodes(const int* __restrict__ cl, int n, const unsigned* __restrict__ off,
                                unsigned* cur, int* __restrict__ node_sorted) {
    int i = blockIdx.x * blockDim.x + threadIdx.x;
    if (i >= n) return;
    int c = cl[i];
    unsigned slot = off[c] + atomicAdd(&cur[c], 1u);
    node_sorted[slot] = i;
}

// ---- pooled features (exact max) + mean positions; 1 wave per cluster ----
__global__ void k_pool(const float* __restrict__ x, const float* __restrict__ pos,
                       const int* __restrict__ node_sorted, const unsigned* __restrict__ off,
                       float* __restrict__ out_x, float* __restrict__ out_pos) {
    int s = blockIdx.x;
    int t = threadIdx.x;
    unsigned beg = off[s], end = off[s + 1];
    float m = -INFINITY;
    float ps = 0.f;
    for (unsigned idx = beg; idx < end; ++idx) {
        int nd = node_sorted[idx];
        m = fmaxf(m, x[(size_t)nd * F + t]);
        if (t < 2) ps += pos[(size_t)nd * 2 + t];
    }
    int cnt = (int)(end - beg);
    out_x[(size_t)s * F + t] = (cnt > 0) ? m : 0.f;
    if (t < 2) out_pos[s * 2 + t] = (cnt > 0) ? ps / (float)cnt : 0.f;
}

// ---- edge keys + per-block coarse histogram (top 8 bits), NO global atomics ----
__global__ void k_ehist(const int* __restrict__ ei, int e, const int* __restrict__ cl,
                        unsigned* __restrict__ keys_tmp, unsigned* __restrict__ table) {
    __shared__ unsigned hist[256];
    int t = threadIdx.x, b = blockIdx.x;
    hist[t] = 0u;
    __syncthreads();
    for (int i = b * 256 + t; i < e; i += GPART * 256) {
        unsigned r = (unsigned)cl[ei[i]];
        unsigned c = (unsigned)cl[ei[e + i]];
        unsigned k = (r << 16) | c;
        keys_tmp[i] = k;
        atomicAdd(&hist[k >> 24], 1u);
    }
    __syncthreads();
    table[t * GPART + b] = hist[t];   // bin-major layout
}

// ---- coalesced coarse partition: stage bin-grouped in LDS, write contiguous runs ----
__global__ void k_partition(const unsigned* __restrict__ keys_tmp, int e,
                            const unsigned* __restrict__ table,
                            unsigned* __restrict__ keys_part) {
    __shared__ unsigned stage[8192];
    __shared__ unsigned h[256], cur[256], tbl_s[256];
    int t = threadIdx.x, b = blockIdx.x;
    h[t] = 0u;
    tbl_s[t] = table[t * GPART + b];
    __syncthreads();
    // phase 1: count
    for (int i = b * 256 + t; i < e; i += GPART * 256)
        atomicAdd(&h[keys_tmp[i] >> 24], 1u);
    __syncthreads();
    // exclusive scan h -> cur (Hillis-Steele over 256)
    unsigned v = h[t];
    cur[t] = v;
    __syncthreads();
    for (int s = 1; s < 256; s <<= 1) {
        unsigned u = (t >= s) ? cur[t - s] : 0u;
        __syncthreads();
        cur[t] += u;
        __syncthreads();
    }
    unsigned incl = cur[t];
    __syncthreads();
    cur[t] = incl - v;                 // exclusive offsets; doubles as placement cursor
    __syncthreads();
    // phase 2: place into LDS (any order within (block,bin) is fine — dups interchangeable)
    for (int i = b * 256 + t; i < e; i += GPART * 256) {
        unsigned k = keys_tmp[i];
        unsigned p = atomicAdd(&cur[k >> 24], 1u);
        stage[p] = k;
    }
    __syncthreads();
    int cnt = (int)cur[255];           // total placed this block
    // phase 3: write contiguous runs per bin
    for (int j = t; j < cnt; j += 256) {
        unsigned k = stage[j];
        unsigned bin = k >> 24;
        unsigned offv = (bin == 0) ? 0u : cur[bin - 1];   // = local bin start
        keys_part[tbl_s[bin] + ((unsigned)j - offv)] = k;
    }
}

// ---- full bitonic sort of each coarse bin in LDS (final order == lexsort) ----
__global__ void k_sortbin(unsigned* __restrict__ keys, const unsigned* __restrict__ table, int e) {
    __shared__ unsigned sh[SORTP];
    int b = blockIdx.x, t = threadIdx.x;
    int beg = (int)table[b * GPART];
    int end = (int)table[(b + 1) * GPART];   // b==255 -> table[TBL] == e
    int len = end - beg;
    if (len <= 1) return;
    if (len <= SORTP) {
        for (int i = t; i < SORTP; i += blockDim.x)
            sh[i] = (i < len) ? keys[beg + i] : 0xFFFFFFFFu;
        __syncthreads();
        for (int k = 2; k <= SORTP; k <<= 1) {
            for (int j = k >> 1; j >= 1; j >>= 1) {
                for (int idx = t; idx < SORTP / 2; idx += blockDim.x) {
                    int i = 2 * idx - (idx & (j - 1));
                    int p = i + j;
                    bool up = ((i & k) == 0);
                    unsigned a = sh[i], c = sh[p];
                    if ((a > c) == up) { sh[i] = c; sh[p] = a; }
                }
                __syncthreads();
            }
        }
        for (int i = t; i < len; i += blockDim.x) keys[beg + i] = sh[i];
    } else {
        if (t == 0) {  // statistically unreachable (bin mean 15625, 5.4 sigma < 16384)
            for (int a = beg + 1; a < end; ++a) {
                unsigned v = keys[a]; int c = a - 1;
                while (c >= beg && keys[c] > v) { keys[c + 1] = keys[c]; --c; }
                keys[c + 1] = v;
            }
        }
    }
}

// ---- flags + e_row/e_col/edge_valid + per-block partial max|cart| ----
__global__ void k_eflags(const unsigned* __restrict__ keys, int e,
                         const float2* __restrict__ pos_pool,
                         float* __restrict__ out_erow, float* __restrict__ out_ecol,
                         float* __restrict__ out_valid, float* __restrict__ pmax) {
    __shared__ float shm[4];
    int i = blockIdx.x * blockDim.x + threadIdx.x;
    float am = 0.f;
    if (i < e) {
        unsigned k = keys[i];
        bool first = (i == 0) || (k != keys[i - 1]);
        unsigned r = k >> 16, c = k & 0xFFFFu;
        bool valid = first && (r != c);
        out_erow[i]  = valid ? (float)r : 0.f;
        out_ecol[i]  = valid ? (float)c : 0.f;
        out_valid[i] = valid ? 1.f : 0.f;
        if (valid) {
            float2 pr = pos_pool[r], pc = pos_pool[c];
            am = fmaxf(fabsf(pr.x - pc.x), fabsf(pr.y - pc.y));
        }
    }
    am = wave_max(am);
    int w = threadIdx.x >> 6;
    if ((threadIdx.x & 63) == 0) shm[w] = am;
    __syncthreads();
    if (threadIdx.x == 0)
        pmax[blockIdx.x] = fmaxf(fmaxf(shm[0], shm[1]), fmaxf(shm[2], shm[3]));
}

__global__ void k_redmax(const float* __restrict__ pmax, int nb, unsigned* hdr) {
    __shared__ float shm[16];
    int t = threadIdx.x;
    float m = 0.f;
    for (int i = t; i < nb; i += blockDim.x) m = fmaxf(m, pmax[i]);
    m = wave_max(m);
    int w = t >> 6;
    if ((t & 63) == 0) shm[w] = m;
    __syncthreads();
    if (t == 0) {
        int nw = (blockDim.x + 63) >> 6;
        for (int i = 1; i < nw; ++i) m = fmaxf(m, shm[i]);
        hdr[2] = (unsigned)__float_as_int(m);
    }
}

// ---- edge_attr = cart / (2*max) + 0.5 ----
__global__ void k_eattr(const unsigned* __restrict__ keys, int e,
                        const float2* __restrict__ pos_pool,
                        const unsigned* __restrict__ hdr, float2* __restrict__ out_attr) {
    int i = blockIdx.x * blockDim.x + threadIdx.x;
    if (i >= e) return;
    unsigned k = keys[i];
    bool first = (i == 0) || (k != keys[i - 1]);
    unsigned r = k >> 16, c = k & 0xFFFFu;
    bool valid = first && (r != c);
    float ax = 0.f, ay = 0.f;
    if (valid) {
        float2 pr = pos_pool[r], pc = pos_pool[c];
        float denom = 2.0f * __int_as_float((int)hdr[2]);
        ax = (pr.x - pc.x) / denom + 0.5f;
        ay = (pr.y - pc.y) / denom + 0.5f;
    }
    out_attr[i] = make_float2(ax, ay);
}

extern "C" void kernel_launch(void* const* d_in, const int* in_sizes, int n_in,
                              void* d_out, int out_size, void* d_ws, size_t ws_size,
                              hipStream_t stream) {
    const float* x    = (const float*)d_in[0];
    const float* pos  = (const float*)d_in[1];
    const int* batch  = (const int*)d_in[2];
    const int* ei     = (const int*)d_in[3];
    const int n = in_sizes[2];
    const int e = in_sizes[3] / 2;

    float* out      = (float*)d_out;
    float* out_x    = out;                                   // [SEG, F]
    float* out_pos  = out_x  + (size_t)SEG * F;              // [SEG, 2]
    float* out_erow = out_pos + (size_t)SEG * 2;             // [E]
    float* out_ecol = out_erow + e;                          // [E]
    float* out_attr = out_ecol + e;                          // [E, 2]
    float* out_val  = out_attr + (size_t)2 * e;              // [E]

    const int nb_n = (n + 255) / 256;
    const int nb_e = (e + 255) / 256;

    char* w = (char*)d_ws;
    unsigned* hdr         = (unsigned*)w;                            // 3 u32 (pad 256)
    int*      cl          = (int*)(w + 256);                         // [n]
    int*      node_sorted = (int*)(w + 256 + (size_t)n * 4);         // [n]
    unsigned* node_cnt    = (unsigned*)(w + 256 + (size_t)n * 8);    // [SEG]
    unsigned* node_cur    = node_cnt + SEG;                          // [SEG]
    unsigned* node_off    = node_cur + SEG;                          // [SEG+1]
    unsigned* table       = node_off + SEG + 1;                      // [TBL+1]
    unsigned* keys_tmp    = table + TBL + 1;                         // [e]
    unsigned* keys_sorted = keys_tmp + e;                            // [e]
    unsigned* blksum      = keys_sorted + e;                         // [128]
    float2*   pmin        = (float2*)(blksum + 128);                 // [MINB]
    float*    pmax        = (float*)(pmin + MINB);                   // [nb_e]

    k_init<<<512, 256, 0, stream>>>(node_cnt, 2 * SEG);              // node_cnt + node_cur
    k_min<<<MINB, 256, 0, stream>>>((const float2*)pos, n, pmin);
    k_minred<<<1, 1024, 0, stream>>>(pmin, MINB, hdr);
    k_cluster<<<nb_n, 256, 0, stream>>>((const float2*)pos, batch, n, hdr, cl, node_cnt);
    k_scan1<<<64, 1024, 0, stream>>>(node_cnt, node_off, blksum);
    k_scan_add<<<64, 1024, 0, stream>>>(node_off, blksum, SEG, (unsigned)n);
    k_scatter_nodes<<<nb_n, 256, 0, stream>>>(cl, n, node_off, node_cur, node_sorted);
    k_pool<<<SEG, 64, 0, stream>>>(x, pos, node_sorted, node_off, out_x, out_pos);

    k_ehist<<<GPART, 256, 0, stream>>>(ei, e, cl, keys_tmp, table);
    k_scan1<<<TBL / 1024, 1024, 0, stream>>>(table, table, blksum);  // in-place ok? NO — separate:
    // (k_scan1 reads cnt[g] then writes off[g]; with cnt==off it reads before writing same slot — safe
    //  since each thread reads its own slot into LDS before any write. In-place is fine.)
    k_scan_add<<<TBL / 1024, 1024, 0, stream>>>(table, blksum, TBL, (unsigned)e);
    k_partition<<<GPART, 256, 0, stream>>>(keys_tmp, e, table, keys_sorted);
    k_sortbin<<<256, 1024, 0, stream>>>(keys_sorted, table, e);

    k_eflags<<<nb_e, 256, 0, stream>>>(keys_sorted, e, (const float2*)out_pos,
                                       out_erow, out_ecol, out_val, pmax);
    k_redmax<<<1, 1024, 0, stream>>>(pmax, nb_e, hdr);
    k_eattr<<<nb_e, 256, 0, stream>>>(keys_sorted, e, (const float2*)out_pos,
                                      hdr, (float2*)out_attr);
}

// Round 4
// 488.337 us; speedup vs baseline: 16980.6354x; 16980.6354x over previous
//
#include <hip/hip_runtime.h>
#include <math.h>

static constexpr int F     = 64;
static constexpr int GRIDV = 64;
static constexpr int SEG   = 16 * GRIDV * GRIDV;   // 65536 clusters
static constexpr int MINB  = 1024;                 // blocks for k_min
static constexpr int GPART = 512;                  // blocks for edge hist/partition
static constexpr int PTHR  = 512;                  // threads for edge hist/partition
static constexpr int NBIN  = 512;                  // coarse bins (top 9 bits of key)
static constexpr int BSH   = 23;                   // key >> 23 -> bin
static constexpr int TBL   = NBIN * GPART;         // 262144 table entries
static constexpr int SORTP = 16384;                // bitonic LDS capacity (64KB)

__device__ __forceinline__ float wave_min(float v) {
    for (int o = 32; o > 0; o >>= 1) v = fminf(v, __shfl_down(v, o));
    return v;
}
__device__ __forceinline__ float wave_max(float v) {
    for (int o = 32; o > 0; o >>= 1) v = fmaxf(v, __shfl_down(v, o));
    return v;
}

// ---- zero counters ----
__global__ void k_init(unsigned* cnts, int ncnt) {
    int i = blockIdx.x * blockDim.x + threadIdx.x;
    int stride = gridDim.x * blockDim.x;
    for (int j = i; j < ncnt; j += stride) cnts[j] = 0u;
}

// ---- per-block partial min of pos ----
__global__ void k_min(const float2* __restrict__ pos, int n, float2* __restrict__ pmin) {
    __shared__ float shx[4], shy[4];
    int stride = gridDim.x * blockDim.x;
    float mx = INFINITY, my = INFINITY;
    for (int i = blockIdx.x * blockDim.x + threadIdx.x; i < n; i += stride) {
        float2 p = pos[i];
        mx = fminf(mx, p.x); my = fminf(my, p.y);
    }
    mx = wave_min(mx); my = wave_min(my);
    int w = threadIdx.x >> 6;
    if ((threadIdx.x & 63) == 0) { shx[w] = mx; shy[w] = my; }
    __syncthreads();
    if (threadIdx.x == 0) {
        mx = fminf(fminf(shx[0], shx[1]), fminf(shx[2], shx[3]));
        my = fminf(fminf(shy[0], shy[1]), fminf(shy[2], shy[3]));
        pmin[blockIdx.x] = make_float2(mx, my);
    }
}

__global__ void k_minred(const float2* __restrict__ pmin, int nb, unsigned* hdr) {
    __shared__ float shx[16], shy[16];
    int t = threadIdx.x;
    float mx = INFINITY, my = INFINITY;
    for (int i = t; i < nb; i += blockDim.x) {
        float2 p = pmin[i];
        mx = fminf(mx, p.x); my = fminf(my, p.y);
    }
    mx = wave_min(mx); my = wave_min(my);
    int w = t >> 6;
    if ((t & 63) == 0) { shx[w] = mx; shy[w] = my; }
    __syncthreads();
    if (t == 0) {
        int nw = (blockDim.x + 63) >> 6;
        for (int i = 1; i < nw; ++i) { mx = fminf(mx, shx[i]); my = fminf(my, shy[i]); }
        hdr[0] = (unsigned)__float_as_int(mx);
        hdr[1] = (unsigned)__float_as_int(my);
    }
}

// ---- per-node cluster id + node histogram ----
__global__ void k_cluster(const float2* __restrict__ pos, const int* __restrict__ batch, int n,
                          const unsigned* __restrict__ hdr, int* __restrict__ cl,
                          unsigned* __restrict__ node_cnt) {
    int i = blockIdx.x * blockDim.x + threadIdx.x;
    if (i >= n) return;
    float sx = __int_as_float((int)hdr[0]);
    float sy = __int_as_float((int)hdr[1]);
    float2 p = pos[i];
    int vx = (int)floorf((p.x - sx) * 64.0f);   // /VOXEL_SIZE == *64 exactly
    int vy = (int)floorf((p.y - sy) * 64.0f);
    vx = min(max(vx, 0), GRIDV - 1);
    vy = min(max(vy, 0), GRIDV - 1);
    int c = batch[i] * (GRIDV * GRIDV) + vy * GRIDV + vx;
    cl[i] = c;
    atomicAdd(&node_cnt[c], 1u);
}

// ---- hierarchical exclusive scan: stage 1 (gridDim*1024 entries) ----
__global__ void k_scan1(const unsigned* __restrict__ cnt, unsigned* __restrict__ off,
                        unsigned* __restrict__ blksum) {
    __shared__ unsigned sh[1024];
    int t = threadIdx.x;
    int g = blockIdx.x * 1024 + t;
    unsigned v = cnt[g];
    sh[t] = v;
    __syncthreads();
    for (int s = 1; s < 1024; s <<= 1) {
        unsigned u = (t >= s) ? sh[t - s] : 0u;
        __syncthreads();
        sh[t] += u;
        __syncthreads();
    }
    off[g] = sh[t] - v;
    if (t == 1023) blksum[blockIdx.x] = sh[1023];
}

// stage 2: add block bases (parallel reduction of blksum[0..b-1]); up to 256 blocks
__global__ void k_scan_add(unsigned* __restrict__ off, const unsigned* __restrict__ blksum,
                           int nblk, int n, unsigned total) {
    __shared__ unsigned sh[256];
    int t = threadIdx.x, b = blockIdx.x;
    if (t < 256) sh[t] = (t < b && t < nblk) ? blksum[t] : 0u;
    __syncthreads();
    for (int s = 128; s > 0; s >>= 1) {
        if (t < s) sh[t] += sh[t + s];
        __syncthreads();
    }
    off[b * 1024 + t] += sh[0];
    if (b == 0 && t == 0) off[n] = total;
}

// ---- scatter nodes into cluster-sorted order (unstable) ----
__global__ void k_scatter_nodes(const int* __restrict__ cl, int n, const unsigned* __restrict__ off,
                                unsigned* cur, int* __restrict__ node_sorted) {
    int i = blockIdx.x * blockDim.x + threadIdx.x;
    if (i >= n) return;
    int c = cl[i];
    unsigned slot = off[c] + atomicAdd(&cur[c], 1u);
    node_sorted[slot] = i;
}

// ---- pooled features (exact max) + mean positions; 1 wave per cluster ----
__global__ void k_pool(const float* __restrict__ x, const float* __restrict__ pos,
                       const int* __restrict__ node_sorted, const unsigned* __restrict__ off,
                       float* __restrict__ out_x, float* __restrict__ out_pos) {
    int s = blockIdx.x;
    int t = threadIdx.x;
    unsigned beg = off[s], end = off[s + 1];
    float m = -INFINITY;
    float ps = 0.f;
    for (unsigned idx = beg; idx < end; ++idx) {
        int nd = node_sorted[idx];
        m = fmaxf(m, x[(size_t)nd * F + t]);
        if (t < 2) ps += pos[(size_t)nd * 2 + t];
    }
    int cnt = (int)(end - beg);
    out_x[(size_t)s * F + t] = (cnt > 0) ? m : 0.f;
    if (t < 2) out_pos[s * 2 + t] = (cnt > 0) ? ps / (float)cnt : 0.f;
}

// ---- edge keys + per-block coarse histogram (top 9 bits), NO global atomics ----
__global__ void k_ehist(const int* __restrict__ ei, int e, const int* __restrict__ cl,
                        unsigned* __restrict__ keys_tmp, unsigned* __restrict__ table) {
    __shared__ unsigned hist[NBIN];
    int t = threadIdx.x, b = blockIdx.x;
    hist[t] = 0u;
    __syncthreads();
    for (int i = b * PTHR + t; i < e; i += GPART * PTHR) {
        unsigned r = (unsigned)cl[ei[i]];
        unsigned c = (unsigned)cl[ei[e + i]];
        unsigned k = (r << 16) | c;
        keys_tmp[i] = k;
        atomicAdd(&hist[k >> BSH], 1u);
    }
    __syncthreads();
    table[t * GPART + b] = hist[t];   // bin-major layout
}

// ---- coalesced coarse partition: stage bin-grouped in LDS, write contiguous runs ----
__global__ void k_partition(const unsigned* __restrict__ keys_tmp, int e,
                            const unsigned* __restrict__ table,
                            unsigned* __restrict__ keys_part) {
    __shared__ unsigned stage[8192];
    __shared__ unsigned h[NBIN], cur[NBIN], tbl_s[NBIN];
    int t = threadIdx.x, b = blockIdx.x;
    h[t] = 0u;
    tbl_s[t] = table[t * GPART + b];
    __syncthreads();
    // phase 1: count
    for (int i = b * PTHR + t; i < e; i += GPART * PTHR)
        atomicAdd(&h[keys_tmp[i] >> BSH], 1u);
    __syncthreads();
    // exclusive scan h -> cur (Hillis-Steele over NBIN with NBIN threads)
    unsigned v = h[t];
    cur[t] = v;
    __syncthreads();
    for (int s = 1; s < NBIN; s <<= 1) {
        unsigned u = (t >= s) ? cur[t - s] : 0u;
        __syncthreads();
        cur[t] += u;
        __syncthreads();
    }
    unsigned incl = cur[t];
    __syncthreads();
    cur[t] = incl - v;                 // exclusive offsets; doubles as placement cursor
    __syncthreads();
    // phase 2: place into LDS (order within (block,bin) irrelevant — dups interchangeable)
    for (int i = b * PTHR + t; i < e; i += GPART * PTHR) {
        unsigned k = keys_tmp[i];
        unsigned p = atomicAdd(&cur[k >> BSH], 1u);
        stage[p] = k;
    }
    __syncthreads();
    int cnt = (int)cur[NBIN - 1];      // total placed this block (== incl total)
    // phase 3: write contiguous runs per bin
    for (int j = t; j < cnt; j += PTHR) {
        unsigned k = stage[j];
        unsigned bin = k >> BSH;
        unsigned offv = (bin == 0) ? 0u : cur[bin - 1];   // local bin start
        keys_part[tbl_s[bin] + ((unsigned)j - offv)] = k;
    }
}

// ---- full sort of each coarse bin in LDS (adaptive-size bitonic) ----
__global__ void k_sortbin(unsigned* __restrict__ keys, const unsigned* __restrict__ table, int e) {
    __shared__ unsigned sh[SORTP];
    int b = blockIdx.x, t = threadIdx.x;
    int beg = (int)table[b * GPART];
    int end = (int)table[(b + 1) * GPART];   // b==NBIN-1 -> table[TBL] == e
    int len = end - beg;
    if (len <= 1) return;
    if (len <= SORTP) {
        int P = 2; while (P < len) P <<= 1;   // adaptive: P=8192 for typical bins
        for (int i = t; i < P; i += blockDim.x)
            sh[i] = (i < len) ? keys[beg + i] : 0xFFFFFFFFu;
        __syncthreads();
        for (int k = 2; k <= P; k <<= 1) {
            for (int j = k >> 1; j >= 1; j >>= 1) {
                for (int idx = t; idx < (P >> 1); idx += blockDim.x) {
                    int i = 2 * idx - (idx & (j - 1));
                    int p = i + j;
                    bool up = ((i & k) == 0);
                    unsigned a = sh[i], c = sh[p];
                    if ((a > c) == up) { sh[i] = c; sh[p] = a; }
                }
                __syncthreads();
            }
        }
        for (int i = t; i < len; i += blockDim.x) keys[beg + i] = sh[i];
    } else {
        // 43-sigma-unreachable fallback: block-parallel odd-even transposition (global mem)
        for (int r = 0; r < len; ++r) {
            for (int j = 2 * t + (r & 1); j + 1 < len; j += 2 * blockDim.x) {
                unsigned a = keys[beg + j], c = keys[beg + j + 1];
                if (a > c) { keys[beg + j] = c; keys[beg + j + 1] = a; }
            }
            __syncthreads();
        }
    }
}

// ---- flags + e_row/e_col/edge_valid + unnormalized cart (NaN sentinel) + partial max ----
__global__ void k_eflags(const unsigned* __restrict__ keys, int e,
                         const float2* __restrict__ pos_pool,
                         float* __restrict__ out_erow, float* __restrict__ out_ecol,
                         float* __restrict__ out_valid, float2* __restrict__ out_attr,
                         float* __restrict__ pmax) {
    __shared__ float shm[4];
    int i = blockIdx.x * blockDim.x + threadIdx.x;
    float am = 0.f;
    if (i < e) {
        unsigned k = keys[i];
        bool first = (i == 0) || (k != keys[i - 1]);
        unsigned r = k >> 16, c = k & 0xFFFFu;
        bool valid = first && (r != c);
        out_erow[i]  = valid ? (float)r : 0.f;
        out_ecol[i]  = valid ? (float)c : 0.f;
        out_valid[i] = valid ? 1.f : 0.f;
        if (valid) {
            float2 pr = pos_pool[r], pc = pos_pool[c];
            float cx = pr.x - pc.x, cy = pr.y - pc.y;
            am = fmaxf(fabsf(cx), fabsf(cy));
            out_attr[i] = make_float2(cx, cy);
        } else {
            out_attr[i] = make_float2(__int_as_float(0x7FC00000), 0.f);  // NaN sentinel
        }
    }
    am = wave_max(am);
    int w = threadIdx.x >> 6;
    if ((threadIdx.x & 63) == 0) shm[w] = am;
    __syncthreads();
    if (threadIdx.x == 0)
        pmax[blockIdx.x] = fmaxf(fmaxf(shm[0], shm[1]), fmaxf(shm[2], shm[3]));
}

__global__ void k_redmax(const float* __restrict__ pmax, int nb, unsigned* hdr) {
    __shared__ float shm[16];
    int t = threadIdx.x;
    float m = 0.f;
    for (int i = t; i < nb; i += blockDim.x) m = fmaxf(m, pmax[i]);
    m = wave_max(m);
    int w = t >> 6;
    if ((t & 63) == 0) shm[w] = m;
    __syncthreads();
    if (t == 0) {
        int nw = (blockDim.x + 63) >> 6;
        for (int i = 1; i < nw; ++i) m = fmaxf(m, shm[i]);
        hdr[2] = (unsigned)__float_as_int(m);
    }
}

// ---- in-place rescale: attr = cart/(2*max) + 0.5 (NaN sentinel -> 0) ----
__global__ void k_rescale(float2* __restrict__ out_attr, int e, const unsigned* __restrict__ hdr) {
    int i = blockIdx.x * blockDim.x + threadIdx.x;
    if (i >= e) return;
    float2 a = out_attr[i];
    float inv = 0.5f / __int_as_float((int)hdr[2]);
    bool valid = (a.x == a.x);
    float ax = valid ? a.x * inv + 0.5f : 0.f;
    float ay = valid ? a.y * inv + 0.5f : 0.f;
    out_attr[i] = make_float2(ax, ay);
}

extern "C" void kernel_launch(void* const* d_in, const int* in_sizes, int n_in,
                              void* d_out, int out_size, void* d_ws, size_t ws_size,
                              hipStream_t stream) {
    const float* x    = (const float*)d_in[0];
    const float* pos  = (const float*)d_in[1];
    const int* batch  = (const int*)d_in[2];
    const int* ei     = (const int*)d_in[3];
    const int n = in_sizes[2];
    const int e = in_sizes[3] / 2;

    float* out      = (float*)d_out;
    float* out_x    = out;                                   // [SEG, F]
    float* out_pos  = out_x  + (size_t)SEG * F;              // [SEG, 2]
    float* out_erow = out_pos + (size_t)SEG * 2;             // [E]
    float* out_ecol = out_erow + e;                          // [E]
    float* out_attr = out_ecol + e;                          // [E, 2]
    float* out_val  = out_attr + (size_t)2 * e;              // [E]

    const int nb_n = (n + 255) / 256;
    const int nb_e = (e + 255) / 256;

    char* w = (char*)d_ws;
    unsigned* hdr         = (unsigned*)w;                            // 3 u32 (pad 256)
    int*      cl          = (int*)(w + 256);                         // [n]
    int*      node_sorted = (int*)(w + 256 + (size_t)n * 4);         // [n]
    unsigned* node_cnt    = (unsigned*)(w + 256 + (size_t)n * 8);    // [SEG]
    unsigned* node_cur    = node_cnt + SEG;                          // [SEG]
    unsigned* node_off    = node_cur + SEG;                          // [SEG+1]
    unsigned* table       = node_off + SEG + 1;                      // [TBL+1]
    unsigned* keys_tmp    = table + TBL + 1;                         // [e]
    unsigned* keys_sorted = keys_tmp + e;                            // [e]
    unsigned* blksum      = keys_sorted + e;                         // [256]
    float2*   pmin        = (float2*)(blksum + 256);                 // [MINB]
    float*    pmax        = (float*)(pmin + MINB);                   // [nb_e]

    k_init<<<512, 256, 0, stream>>>(node_cnt, 2 * SEG);              // node_cnt + node_cur
    k_min<<<MINB, 256, 0, stream>>>((const float2*)pos, n, pmin);
    k_minred<<<1, 1024, 0, stream>>>(pmin, MINB, hdr);
    k_cluster<<<nb_n, 256, 0, stream>>>((const float2*)pos, batch, n, hdr, cl, node_cnt);
    k_scan1<<<SEG / 1024, 1024, 0, stream>>>(node_cnt, node_off, blksum);
    k_scan_add<<<SEG / 1024, 1024, 0, stream>>>(node_off, blksum, SEG / 1024, SEG, (unsigned)n);
    k_scatter_nodes<<<nb_n, 256, 0, stream>>>(cl, n, node_off, node_cur, node_sorted);
    k_pool<<<SEG, 64, 0, stream>>>(x, pos, node_sorted, node_off, out_x, out_pos);

    k_ehist<<<GPART, PTHR, 0, stream>>>(ei, e, cl, keys_tmp, table);
    k_scan1<<<TBL / 1024, 1024, 0, stream>>>(table, table, blksum);   // in-place safe (own-slot RAW)
    k_scan_add<<<TBL / 1024, 1024, 0, stream>>>(table, blksum, TBL / 1024, TBL, (unsigned)e);
    k_partition<<<GPART, PTHR, 0, stream>>>(keys_tmp, e, table, keys_sorted);
    k_sortbin<<<NBIN, 1024, 0, stream>>>(keys_sorted, table, e);

    k_eflags<<<nb_e, 256, 0, stream>>>(keys_sorted, e, (const float2*)out_pos,
                                       out_erow, out_ecol, out_val, (float2*)out_attr, pmax);
    k_redmax<<<1, 1024, 0, stream>>>(pmax, nb_e, hdr);
    k_rescale<<<nb_e, 256, 0, stream>>>((float2*)out_attr, e, hdr);
}

// Round 5
// 410.515 us; speedup vs baseline: 20199.6780x; 1.1896x over previous
//
#include <hip/hip_runtime.h>
#include <math.h>

static constexpr int F     = 64;
static constexpr int GRIDV = 64;
static constexpr int SEG   = 16 * GRIDV * GRIDV;   // 65536 clusters
static constexpr int MINB  = 1024;                 // blocks for k_min
// edge pipeline
static constexpr int GPART = 512;                  // blocks for edge hist/partition
static constexpr int PTHR  = 512;                  // threads for edge hist/partition
static constexpr int NBIN  = 512;                  // coarse bins (top 9 bits)
static constexpr int BSH   = 23;                   // key >> 23 -> coarse bin
static constexpr int ETBL  = NBIN * GPART;         // 262144
// node pipeline
static constexpr int NGP   = 256;                  // blocks for node partition
static constexpr int NTH   = 256;                  // threads for node partition
static constexpr int NTBL  = NBIN * NGP;           // 131072

__device__ __forceinline__ float wave_min(float v) {
    for (int o = 32; o > 0; o >>= 1) v = fminf(v, __shfl_down(v, o));
    return v;
}
__device__ __forceinline__ float wave_max(float v) {
    for (int o = 32; o > 0; o >>= 1) v = fmaxf(v, __shfl_down(v, o));
    return v;
}

// ---- zero node counters ----
__global__ void k_init(unsigned* cnts, int ncnt) {
    int i = blockIdx.x * blockDim.x + threadIdx.x;
    int stride = gridDim.x * blockDim.x;
    for (int j = i; j < ncnt; j += stride) cnts[j] = 0u;
}

// ---- per-block partial min of pos ----
__global__ void k_min(const float2* __restrict__ pos, int n, float2* __restrict__ pmin) {
    __shared__ float shx[4], shy[4];
    int stride = gridDim.x * blockDim.x;
    float mx = INFINITY, my = INFINITY;
    for (int i = blockIdx.x * blockDim.x + threadIdx.x; i < n; i += stride) {
        float2 p = pos[i];
        mx = fminf(mx, p.x); my = fminf(my, p.y);
    }
    mx = wave_min(mx); my = wave_min(my);
    int w = threadIdx.x >> 6;
    if ((threadIdx.x & 63) == 0) { shx[w] = mx; shy[w] = my; }
    __syncthreads();
    if (threadIdx.x == 0) {
        mx = fminf(fminf(shx[0], shx[1]), fminf(shx[2], shx[3]));
        my = fminf(fminf(shy[0], shy[1]), fminf(shy[2], shy[3]));
        pmin[blockIdx.x] = make_float2(mx, my);
    }
}

__global__ void k_minred(const float2* __restrict__ pmin, int nb, unsigned* hdr) {
    __shared__ float shx[16], shy[16];
    int t = threadIdx.x;
    float mx = INFINITY, my = INFINITY;
    for (int i = t; i < nb; i += blockDim.x) {
        float2 p = pmin[i];
        mx = fminf(mx, p.x); my = fminf(my, p.y);
    }
    mx = wave_min(mx); my = wave_min(my);
    int w = t >> 6;
    if ((t & 63) == 0) { shx[w] = mx; shy[w] = my; }
    __syncthreads();
    if (t == 0) {
        int nw = (blockDim.x + 63) >> 6;
        for (int i = 1; i < nw; ++i) { mx = fminf(mx, shx[i]); my = fminf(my, shy[i]); }
        hdr[0] = (unsigned)__float_as_int(mx);
        hdr[1] = (unsigned)__float_as_int(my);
    }
}

// ---- cluster ids + full histogram (global atomics) + coarse 512-bin table ----
__global__ void k_cluster(const float2* __restrict__ pos, const int* __restrict__ batch, int n,
                          const unsigned* __restrict__ hdr, int* __restrict__ cl,
                          unsigned* __restrict__ node_cnt, unsigned* __restrict__ ntable) {
    __shared__ unsigned hist[NBIN];
    int t = threadIdx.x, b = blockIdx.x;
    for (int j = t; j < NBIN; j += NTH) hist[j] = 0u;
    __syncthreads();
    float sx = __int_as_float((int)hdr[0]);
    float sy = __int_as_float((int)hdr[1]);
    for (int i = b * NTH + t; i < n; i += NGP * NTH) {
        float2 p = pos[i];
        int vx = min(max((int)floorf((p.x - sx) * 64.0f), 0), GRIDV - 1);
        int vy = min(max((int)floorf((p.y - sy) * 64.0f), 0), GRIDV - 1);
        int c = batch[i] * (GRIDV * GRIDV) + vy * GRIDV + vx;
        cl[i] = c;
        atomicAdd(&node_cnt[c], 1u);
        atomicAdd(&hist[(unsigned)c >> 7], 1u);
    }
    __syncthreads();
    for (int j = t; j < NBIN; j += NTH) ntable[j * NGP + b] = hist[j];
}

// ---- hierarchical exclusive scan: stage 1 (gridDim*1024 entries) ----
__global__ void k_scan1(const unsigned* __restrict__ cnt, unsigned* __restrict__ off,
                        unsigned* __restrict__ blksum) {
    __shared__ unsigned sh[1024];
    int t = threadIdx.x;
    int g = blockIdx.x * 1024 + t;
    unsigned v = cnt[g];
    sh[t] = v;
    __syncthreads();
    for (int s = 1; s < 1024; s <<= 1) {
        unsigned u = (t >= s) ? sh[t - s] : 0u;
        __syncthreads();
        sh[t] += u;
        __syncthreads();
    }
    off[g] = sh[t] - v;
    if (t == 1023) blksum[blockIdx.x] = sh[1023];
}

// stage 2: add block bases; up to 256 stage-1 blocks
__global__ void k_scan_add(unsigned* __restrict__ off, const unsigned* __restrict__ blksum,
                           int nblk, int n, unsigned total) {
    __shared__ unsigned sh[256];
    int t = threadIdx.x, b = blockIdx.x;
    if (t < 256) sh[t] = (t < b && t < nblk) ? blksum[t] : 0u;
    __syncthreads();
    for (int s = 128; s > 0; s >>= 1) {
        if (t < s) sh[t] += sh[t + s];
        __syncthreads();
    }
    off[b * 1024 + t] += sh[0];
    if (b == 0 && t == 0) off[n] = total;
}

// ---- node coarse partition: stage (cluster,node) pairs in LDS, write coalesced runs ----
__global__ __launch_bounds__(NTH) void k_npart(const int* __restrict__ cl, int n,
                       const unsigned* __restrict__ ntable,
                       unsigned* __restrict__ pc, unsigned* __restrict__ pn) {
    __shared__ unsigned stage_c[4096], stage_n[4096];
    __shared__ unsigned h[NBIN], cur[NBIN], tbl_s[NBIN];
    __shared__ unsigned ss[NTH];
    int t = threadIdx.x, b = blockIdx.x;
    for (int j = t; j < NBIN; j += NTH) { h[j] = 0u; tbl_s[j] = ntable[j * NGP + b]; }
    __syncthreads();
    for (int i = b * NTH + t; i < n; i += NGP * NTH)
        atomicAdd(&h[((unsigned)cl[i]) >> 7], 1u);
    __syncthreads();
    unsigned a0 = h[2 * t], a1 = h[2 * t + 1];
    ss[t] = a0 + a1;
    __syncthreads();
    for (int s = 1; s < NTH; s <<= 1) {
        unsigned u = (t >= s) ? ss[t - s] : 0u;
        __syncthreads();
        ss[t] += u;
        __syncthreads();
    }
    unsigned base = ss[t] - (a0 + a1);
    cur[2 * t] = base;
    cur[2 * t + 1] = base + a0;
    __syncthreads();
    for (int i = b * NTH + t; i < n; i += NGP * NTH) {
        unsigned c = (unsigned)cl[i];
        unsigned p = atomicAdd(&cur[c >> 7], 1u);
        stage_c[p] = c; stage_n[p] = (unsigned)i;
    }
    __syncthreads();
    int cnt = (int)ss[NTH - 1];
    for (int j = t; j < cnt; j += NTH) {
        unsigned c = stage_c[j];
        unsigned bin = c >> 7;
        unsigned start = cur[bin] - h[bin];      // cur is now bin end; start = end - count
        unsigned g = tbl_s[bin] + ((unsigned)j - start);
        pc[g] = c; pn[g] = stage_n[j];
    }
}

// ---- group nodes into node_off layout (one block per coarse bin; L2-local writes) ----
__global__ void k_ngroup(const unsigned* __restrict__ pc, const unsigned* __restrict__ pn,
                         const unsigned* __restrict__ node_off,
                         int* __restrict__ node_sorted) {
    __shared__ unsigned cur[128];
    int b = blockIdx.x, t = threadIdx.x;
    if (t < 128) cur[t] = node_off[b * 128 + t];
    __syncthreads();
    int beg = (int)node_off[b * 128];
    int end = (int)node_off[(b + 1) * 128];
    for (int i = beg + t; i < end; i += blockDim.x) {
        unsigned c = pc[i];
        unsigned slot = atomicAdd(&cur[c & 127u], 1u);
        node_sorted[slot] = (int)pn[i];
    }
}

// ---- pooled features + mean positions; 4 waves/block, 2-way unrolled ----
__global__ __launch_bounds__(256) void k_pool(const float* __restrict__ x,
                      const float2* __restrict__ pos,
                      const int* __restrict__ node_sorted, const unsigned* __restrict__ off,
                      float* __restrict__ out_x, float2* __restrict__ out_pos) {
    int wid  = threadIdx.x >> 6;
    int lane = threadIdx.x & 63;
    int s = blockIdx.x * 4 + wid;
    unsigned beg = off[s], end = off[s + 1];
    float m0 = -INFINITY, m1 = -INFINITY;
    float psx = 0.f, psy = 0.f;
    unsigned i = beg;
    for (; i + 2 <= end; i += 2) {
        int nd0 = node_sorted[i], nd1 = node_sorted[i + 1];
        m0 = fmaxf(m0, x[(size_t)nd0 * F + lane]);
        m1 = fmaxf(m1, x[(size_t)nd1 * F + lane]);
        if (lane == 0) {
            float2 p0 = pos[nd0], p1 = pos[nd1];
            psx += p0.x + p1.x; psy += p0.y + p1.y;
        }
    }
    if (i < end) {
        int nd0 = node_sorted[i];
        m0 = fmaxf(m0, x[(size_t)nd0 * F + lane]);
        if (lane == 0) { float2 p0 = pos[nd0]; psx += p0.x; psy += p0.y; }
    }
    int cnt = (int)(end - beg);
    out_x[(size_t)s * F + lane] = (cnt > 0) ? fmaxf(m0, m1) : 0.f;
    if (lane == 0)
        out_pos[s] = (cnt > 0) ? make_float2(psx / (float)cnt, psy / (float)cnt)
                               : make_float2(0.f, 0.f);
}

// ---- edge keys + coarse histogram + fused max|cart| (dedup-invariant) ----
__global__ __launch_bounds__(PTHR) void k_ehist(const int* __restrict__ ei, int e,
                        const int* __restrict__ cl, const float2* __restrict__ pos_pool,
                        unsigned* __restrict__ keysA, unsigned* __restrict__ etable,
                        float* __restrict__ pmax) {
    __shared__ unsigned hist[NBIN];
    __shared__ float shm[PTHR / 64];
    int t = threadIdx.x, b = blockIdx.x;
    for (int j = t; j < NBIN; j += PTHR) hist[j] = 0u;
    __syncthreads();
    float am = 0.f;
    for (int i = b * PTHR + t; i < e; i += GPART * PTHR) {
        unsigned r = (unsigned)cl[ei[i]];
        unsigned c = (unsigned)cl[ei[e + i]];
        unsigned k = (r << 16) | c;
        keysA[i] = k;
        atomicAdd(&hist[k >> BSH], 1u);
        if (r != c) {
            float2 pr = pos_pool[r], pcc = pos_pool[c];
            am = fmaxf(am, fmaxf(fabsf(pr.x - pcc.x), fabsf(pr.y - pcc.y)));
        }
    }
    __syncthreads();
    for (int j = t; j < NBIN; j += PTHR) etable[j * GPART + b] = hist[j];
    am = wave_max(am);
    if ((t & 63) == 0) shm[t >> 6] = am;
    __syncthreads();
    if (t == 0) {
        float m = shm[0];
        for (int i2 = 1; i2 < PTHR / 64; ++i2) m = fmaxf(m, shm[i2]);
        pmax[b] = m;
    }
}

__global__ void k_redmax(const float* __restrict__ pmax, int nb, unsigned* hdr) {
    __shared__ float shm[16];
    int t = threadIdx.x;
    float m = 0.f;
    for (int i = t; i < nb; i += blockDim.x) m = fmaxf(m, pmax[i]);
    m = wave_max(m);
    int w = t >> 6;
    if ((t & 63) == 0) shm[w] = m;
    __syncthreads();
    if (t == 0) {
        int nw = (blockDim.x + 63) >> 6;
        for (int i = 1; i < nw; ++i) m = fmaxf(m, shm[i]);
        hdr[2] = (unsigned)__float_as_int(m);
    }
}

// ---- coalesced coarse partition of edge keys (A -> B) ----
__global__ __launch_bounds__(PTHR) void k_partition(const unsigned* __restrict__ keysA, int e,
                            const unsigned* __restrict__ etable,
                            unsigned* __restrict__ keysB) {
    __shared__ unsigned stage[8192];
    __shared__ unsigned h[NBIN], cur[NBIN], tbl_s[NBIN];
    int t = threadIdx.x, b = blockIdx.x;
    h[t] = 0u;
    tbl_s[t] = etable[t * GPART + b];
    __syncthreads();
    for (int i = b * PTHR + t; i < e; i += GPART * PTHR)
        atomicAdd(&h[keysA[i] >> BSH], 1u);
    __syncthreads();
    unsigned v = h[t];
    cur[t] = v;
    __syncthreads();
    for (int s = 1; s < NBIN; s <<= 1) {
        unsigned u = (t >= s) ? cur[t - s] : 0u;
        __syncthreads();
        cur[t] += u;
        __syncthreads();
    }
    unsigned incl = cur[t];
    __syncthreads();
    cur[t] = incl - v;
    __syncthreads();
    for (int i = b * PTHR + t; i < e; i += GPART * PTHR) {
        unsigned k = keysA[i];
        unsigned p = atomicAdd(&cur[k >> BSH], 1u);
        stage[p] = k;
    }
    __syncthreads();
    int cnt = (int)cur[NBIN - 1];
    for (int j = t; j < cnt; j += PTHR) {
        unsigned k = stage[j];
        unsigned bin = k >> BSH;
        unsigned start = cur[bin] - h[bin];
        keysB[tbl_s[bin] + ((unsigned)j - start)] = k;
    }
}

// ---- 13-bit LDS counting sort per coarse bin (B -> A); no capacity limit ----
__global__ __launch_bounds__(512) void k_subsort(const unsigned* __restrict__ src,
                         unsigned* __restrict__ dst, const unsigned* __restrict__ table) {
    __shared__ unsigned hist[8192];     // slot(d) = (d&15)*512 + (d>>4)
    __shared__ unsigned ss[512];
    int b = blockIdx.x, t = threadIdx.x;
    int beg = (int)table[b * GPART];
    int end = (int)table[(b + 1) * GPART];
    for (int j = t; j < 8192; j += 512) hist[j] = 0u;
    __syncthreads();
    for (int i = beg + t; i < end; i += 512) {
        unsigned d = (src[i] >> 10) & 8191u;
        atomicAdd(&hist[((d & 15u) << 9) | (d >> 4)], 1u);
    }
    __syncthreads();
    unsigned loc[16];
    unsigned s = 0;
    #pragma unroll
    for (int u = 0; u < 16; ++u) { loc[u] = s; s += hist[u * 512 + t]; }
    ss[t] = s;
    __syncthreads();
    for (int st = 1; st < 512; st <<= 1) {
        unsigned u2 = (t >= st) ? ss[t - st] : 0u;
        __syncthreads();
        ss[t] += u2;
        __syncthreads();
    }
    unsigned base = (unsigned)beg + ss[t] - s;
    #pragma unroll
    for (int u = 0; u < 16; ++u) hist[u * 512 + t] = base + loc[u];
    __syncthreads();
    for (int i = beg + t; i < end; i += 512) {
        unsigned k = src[i];
        unsigned d = (k >> 10) & 8191u;
        unsigned p = atomicAdd(&hist[((d & 15u) << 9) | (d >> 4)], 1u);
        dst[p] = k;
    }
}

// ---- finish: sort equal-top-22-bit micro-runs by low 10 bits (in place) ----
__global__ void k_runsort(unsigned* __restrict__ keys, int e) {
    int i = blockIdx.x * blockDim.x + threadIdx.x;
    if (i >= e) return;
    unsigned hi = keys[i] >> 10;
    if (i > 0 && (keys[i - 1] >> 10) == hi) return;   // not a run start
    int j = i + 1;
    while (j < e && (keys[j] >> 10) == hi) ++j;
    for (int a = i + 1; a < j; ++a) {                 // insertion sort (runs are tiny)
        unsigned v = keys[a];
        int b2 = a - 1;
        while (b2 >= i && keys[b2] > v) { keys[b2 + 1] = keys[b2]; --b2; }
        keys[b2 + 1] = v;
    }
}

// ---- final edge outputs ----
__global__ void k_eflags(const unsigned* __restrict__ keys, int e,
                         const float2* __restrict__ pos_pool, const unsigned* __restrict__ hdr,
                         float* __restrict__ out_erow, float* __restrict__ out_ecol,
                         float* __restrict__ out_valid, float2* __restrict__ out_attr) {
    int i = blockIdx.x * blockDim.x + threadIdx.x;
    if (i >= e) return;
    unsigned k = keys[i];
    bool first = (i == 0) || (k != keys[i - 1]);
    unsigned r = k >> 16, c = k & 0xFFFFu;
    bool valid = first && (r != c);
    float ax = 0.f, ay = 0.f;
    if (valid) {
        float2 pr = pos_pool[r], pcc = pos_pool[c];
        float denom = 2.0f * __int_as_float((int)hdr[2]);
        ax = (pr.x - pcc.x) / denom + 0.5f;
        ay = (pr.y - pcc.y) / denom + 0.5f;
    }
    out_erow[i]  = valid ? (float)r : 0.f;
    out_ecol[i]  = valid ? (float)c : 0.f;
    out_valid[i] = valid ? 1.f : 0.f;
    out_attr[i]  = make_float2(ax, ay);
}

extern "C" void kernel_launch(void* const* d_in, const int* in_sizes, int n_in,
                              void* d_out, int out_size, void* d_ws, size_t ws_size,
                              hipStream_t stream) {
    const float* x    = (const float*)d_in[0];
    const float* pos  = (const float*)d_in[1];
    const int* batch  = (const int*)d_in[2];
    const int* ei     = (const int*)d_in[3];
    const int n = in_sizes[2];
    const int e = in_sizes[3] / 2;

    float* out      = (float*)d_out;
    float* out_x    = out;                                   // [SEG, F]
    float* out_pos  = out_x  + (size_t)SEG * F;              // [SEG, 2]
    float* out_erow = out_pos + (size_t)SEG * 2;             // [E]
    float* out_ecol = out_erow + e;                          // [E]
    float* out_attr = out_ecol + e;                          // [E, 2]
    float* out_val  = out_attr + (size_t)2 * e;              // [E]

    const int nb_e = (e + 255) / 256;

    char* w = (char*)d_ws;
    unsigned* hdr         = (unsigned*)w;                            // 3 u32 (pad 256)
    int*      cl          = (int*)(w + 256);                         // [n]
    int*      node_sorted = (int*)(w + 256 + (size_t)n * 4);         // [n]
    unsigned* node_cnt    = (unsigned*)(w + 256 + (size_t)n * 8);    // [SEG]
    unsigned* node_off    = node_cnt + SEG;                          // [SEG+1]
    unsigned* etable      = node_off + SEG + 1;                      // [ETBL+1] (also ntable)
    unsigned* keysA       = etable + ETBL + 1;                       // [e]  (alias: pc)
    unsigned* keysB       = keysA + e;                               // [e]  (alias: pn)
    unsigned* blksum      = keysB + e;                               // [256]
    float2*   pmin        = (float2*)(blksum + 256);                 // [MINB]
    float*    pmax        = (float*)(pmin + MINB);                   // [GPART]
    unsigned* ntable      = etable;                                  // lifetime-disjoint alias
    unsigned* pc          = keysA;
    unsigned* pn          = keysB;

    // node side
    k_init<<<256, 256, 0, stream>>>(node_cnt, SEG);
    k_min<<<MINB, 256, 0, stream>>>((const float2*)pos, n, pmin);
    k_minred<<<1, 1024, 0, stream>>>(pmin, MINB, hdr);
    k_cluster<<<NGP, NTH, 0, stream>>>((const float2*)pos, batch, n, hdr, cl, node_cnt, ntable);
    k_scan1<<<SEG / 1024, 1024, 0, stream>>>(node_cnt, node_off, blksum);
    k_scan_add<<<SEG / 1024, 1024, 0, stream>>>(node_off, blksum, SEG / 1024, SEG, (unsigned)n);
    k_scan1<<<NTBL / 1024, 1024, 0, stream>>>(ntable, ntable, blksum);
    k_scan_add<<<NTBL / 1024, 1024, 0, stream>>>(ntable, blksum, NTBL / 1024, NTBL, (unsigned)n);
    k_npart<<<NGP, NTH, 0, stream>>>(cl, n, ntable, pc, pn);
    k_ngroup<<<NBIN, 256, 0, stream>>>(pc, pn, node_off, node_sorted);
    k_pool<<<SEG / 4, 256, 0, stream>>>(x, (const float2*)pos, node_sorted, node_off,
                                        out_x, (float2*)out_pos);
    // edge side
    k_ehist<<<GPART, PTHR, 0, stream>>>(ei, e, cl, (const float2*)out_pos, keysA, etable, pmax);
    k_redmax<<<1, 512, 0, stream>>>(pmax, GPART, hdr);
    k_scan1<<<ETBL / 1024, 1024, 0, stream>>>(etable, etable, blksum);
    k_scan_add<<<ETBL / 1024, 1024, 0, stream>>>(etable, blksum, ETBL / 1024, ETBL, (unsigned)e);
    k_partition<<<GPART, PTHR, 0, stream>>>(keysA, e, etable, keysB);
    k_subsort<<<NBIN, 512, 0, stream>>>(keysB, keysA, etable);
    k_runsort<<<nb_e, 256, 0, stream>>>(keysA, e);
    k_eflags<<<nb_e, 256, 0, stream>>>(keysA, e, (const float2*)out_pos, hdr,
                                       out_erow, out_ecol, out_val, (float2*)out_attr);
}

// Round 6
// 312.554 us; speedup vs baseline: 26530.7322x; 1.3134x over previous
//
#include <hip/hip_runtime.h>
#include <math.h>

static constexpr int F     = 64;
static constexpr int GRIDV = 64;
static constexpr int SEG   = 16 * GRIDV * GRIDV;   // 65536 clusters
static constexpr int MINB  = 1024;                 // blocks for k_min
// edge pipeline
static constexpr int GPART = 512;                  // blocks for edge hist/partition
static constexpr int PTHR  = 512;                  // threads for edge hist/partition
static constexpr int NBIN  = 512;                  // coarse bins (top 9 bits)
static constexpr int BSH   = 23;                   // key >> 23 -> coarse bin
static constexpr int ETBL  = NBIN * GPART;         // 262144
static constexpr int SCAP  = 10240;                // subsort LDS staging cap (+27 sigma)
// node pipeline
static constexpr int NGP   = 512;                  // blocks for node partition
static constexpr int NTH   = 256;                  // threads for node partition
static constexpr int NTBL  = NBIN * NGP;           // 262144

__device__ __forceinline__ float wave_min(float v) {
    for (int o = 32; o > 0; o >>= 1) v = fminf(v, __shfl_down(v, o));
    return v;
}
__device__ __forceinline__ float wave_max(float v) {
    for (int o = 32; o > 0; o >>= 1) v = fmaxf(v, __shfl_down(v, o));
    return v;
}

// ---- per-block partial min of pos ----
__global__ void k_min(const float2* __restrict__ pos, int n, float2* __restrict__ pmin) {
    __shared__ float shx[4], shy[4];
    int stride = gridDim.x * blockDim.x;
    float mx = INFINITY, my = INFINITY;
    for (int i = blockIdx.x * blockDim.x + threadIdx.x; i < n; i += stride) {
        float2 p = pos[i];
        mx = fminf(mx, p.x); my = fminf(my, p.y);
    }
    mx = wave_min(mx); my = wave_min(my);
    int w = threadIdx.x >> 6;
    if ((threadIdx.x & 63) == 0) { shx[w] = mx; shy[w] = my; }
    __syncthreads();
    if (threadIdx.x == 0) {
        mx = fminf(fminf(shx[0], shx[1]), fminf(shx[2], shx[3]));
        my = fminf(fminf(shy[0], shy[1]), fminf(shy[2], shy[3]));
        pmin[blockIdx.x] = make_float2(mx, my);
    }
}

__global__ void k_minred(const float2* __restrict__ pmin, int nb, unsigned* hdr) {
    __shared__ float shx[16], shy[16];
    int t = threadIdx.x;
    float mx = INFINITY, my = INFINITY;
    for (int i = t; i < nb; i += blockDim.x) {
        float2 p = pmin[i];
        mx = fminf(mx, p.x); my = fminf(my, p.y);
    }
    mx = wave_min(mx); my = wave_min(my);
    int w = t >> 6;
    if ((t & 63) == 0) { shx[w] = mx; shy[w] = my; }
    __syncthreads();
    if (t == 0) {
        int nw = (blockDim.x + 63) >> 6;
        for (int i = 1; i < nw; ++i) { mx = fminf(mx, shx[i]); my = fminf(my, shy[i]); }
        hdr[0] = (unsigned)__float_as_int(mx);
        hdr[1] = (unsigned)__float_as_int(my);
    }
}

// ---- cluster ids + coarse 512-bin per-block table (no global atomics) ----
__global__ __launch_bounds__(NTH) void k_cluster(const float2* __restrict__ pos,
                          const int* __restrict__ batch, int n,
                          const unsigned* __restrict__ hdr, int* __restrict__ cl,
                          unsigned* __restrict__ ntable) {
    __shared__ unsigned hist[NBIN];
    int t = threadIdx.x, b = blockIdx.x;
    for (int j = t; j < NBIN; j += NTH) hist[j] = 0u;
    __syncthreads();
    float sx = __int_as_float((int)hdr[0]);
    float sy = __int_as_float((int)hdr[1]);
    for (int i = b * NTH + t; i < n; i += NGP * NTH) {
        float2 p = pos[i];
        int vx = min(max((int)floorf((p.x - sx) * 64.0f), 0), GRIDV - 1);
        int vy = min(max((int)floorf((p.y - sy) * 64.0f), 0), GRIDV - 1);
        int c = batch[i] * (GRIDV * GRIDV) + vy * GRIDV + vx;
        cl[i] = c;
        atomicAdd(&hist[(unsigned)c >> 7], 1u);
    }
    __syncthreads();
    for (int j = t; j < NBIN; j += NTH) ntable[j * NGP + b] = hist[j];
}

// ---- hierarchical exclusive scan: stage 1 (gridDim*1024 entries) ----
__global__ void k_scan1(const unsigned* __restrict__ cnt, unsigned* __restrict__ off,
                        unsigned* __restrict__ blksum) {
    __shared__ unsigned sh[1024];
    int t = threadIdx.x;
    int g = blockIdx.x * 1024 + t;
    unsigned v = cnt[g];
    sh[t] = v;
    __syncthreads();
    for (int s = 1; s < 1024; s <<= 1) {
        unsigned u = (t >= s) ? sh[t - s] : 0u;
        __syncthreads();
        sh[t] += u;
        __syncthreads();
    }
    off[g] = sh[t] - v;
    if (t == 1023) blksum[blockIdx.x] = sh[1023];
}

// stage 2: add block bases; up to 256 stage-1 blocks
__global__ void k_scan_add(unsigned* __restrict__ off, const unsigned* __restrict__ blksum,
                           int nblk, int n, unsigned total) {
    __shared__ unsigned sh[256];
    int t = threadIdx.x, b = blockIdx.x;
    if (t < 256) sh[t] = (t < b && t < nblk) ? blksum[t] : 0u;
    __syncthreads();
    for (int s = 128; s > 0; s >>= 1) {
        if (t < s) sh[t] += sh[t + s];
        __syncthreads();
    }
    off[b * 1024 + t] += sh[0];
    if (b == 0 && t == 0) off[n] = total;
}

// ---- node coarse partition: (cluster,node,pos) staged in LDS, coalesced runs out ----
__global__ __launch_bounds__(NTH) void k_npart(const int* __restrict__ cl,
                       const float2* __restrict__ pos, int n,
                       const unsigned* __restrict__ ntable,
                       unsigned* __restrict__ pc, unsigned* __restrict__ pn,
                       float2* __restrict__ ppos) {
    __shared__ unsigned stage_c[2048], stage_n[2048];
    __shared__ float stage_px[2048], stage_py[2048];
    __shared__ unsigned h[NBIN], cur[NBIN], tbl_s[NBIN];
    __shared__ unsigned ss[NTH];
    int t = threadIdx.x, b = blockIdx.x;
    for (int j = t; j < NBIN; j += NTH) { h[j] = 0u; tbl_s[j] = ntable[j * NGP + b]; }
    __syncthreads();
    for (int i = b * NTH + t; i < n; i += NGP * NTH)
        atomicAdd(&h[((unsigned)cl[i]) >> 7], 1u);
    __syncthreads();
    unsigned a0 = h[2 * t], a1 = h[2 * t + 1];
    ss[t] = a0 + a1;
    __syncthreads();
    for (int s = 1; s < NTH; s <<= 1) {
        unsigned u = (t >= s) ? ss[t - s] : 0u;
        __syncthreads();
        ss[t] += u;
        __syncthreads();
    }
    unsigned base = ss[t] - (a0 + a1);
    cur[2 * t] = base;
    cur[2 * t + 1] = base + a0;
    __syncthreads();
    for (int i = b * NTH + t; i < n; i += NGP * NTH) {
        unsigned c = (unsigned)cl[i];
        float2 p = pos[i];
        unsigned q = atomicAdd(&cur[c >> 7], 1u);
        stage_c[q] = c; stage_n[q] = (unsigned)i;
        stage_px[q] = p.x; stage_py[q] = p.y;
    }
    __syncthreads();
    int cnt = (int)ss[NTH - 1];
    for (int j = t; j < cnt; j += NTH) {
        unsigned c = stage_c[j];
        unsigned bin = c >> 7;
        unsigned start = cur[bin] - h[bin];      // cur is bin end; start = end - count
        unsigned g = tbl_s[bin] + ((unsigned)j - start);
        pc[g] = c; pn[g] = stage_n[j];
        ppos[g] = make_float2(stage_px[j], stage_py[j]);
    }
}

// ---- per coarse bin: derive node_off, pos means, and grouped node order ----
__global__ __launch_bounds__(256) void k_ngroup(const unsigned* __restrict__ pc,
                         const unsigned* __restrict__ pn, const float2* __restrict__ ppos,
                         const unsigned* __restrict__ ntable, int n,
                         unsigned* __restrict__ node_off, int* __restrict__ node_sorted,
                         float2* __restrict__ out_pos) {
    __shared__ unsigned cnt[128], sc[128], cur[128];
    __shared__ float psx[128], psy[128];
    int b = blockIdx.x, t = threadIdx.x;
    if (t < 128) { cnt[t] = 0u; psx[t] = 0.f; psy[t] = 0.f; }
    __syncthreads();
    int beg = (int)ntable[b * NGP];
    int end = (int)ntable[(b + 1) * NGP];    // b==NBIN-1 -> ntable[NTBL]==n
    for (int i = beg + t; i < end; i += 256) {
        unsigned c = pc[i] & 127u;
        float2 p = ppos[i];
        atomicAdd(&cnt[c], 1u);
        atomicAdd(&psx[c], p.x);
        atomicAdd(&psy[c], p.y);
    }
    __syncthreads();
    if (t < 128) sc[t] = cnt[t];
    __syncthreads();
    for (int s = 1; s < 128; s <<= 1) {
        unsigned u = (t >= s && t < 128) ? sc[t - s] : 0u;
        __syncthreads();
        if (t < 128) sc[t] += u;
        __syncthreads();
    }
    if (t < 128) {
        unsigned basec = (unsigned)beg + sc[t] - cnt[t];
        node_off[b * 128 + t] = basec;
        cur[t] = basec;
        unsigned c2 = cnt[t];
        out_pos[b * 128 + t] = c2 ? make_float2(psx[t] / (float)c2, psy[t] / (float)c2)
                                  : make_float2(0.f, 0.f);
    }
    if (b == NBIN - 1 && t == 0) node_off[SEG] = (unsigned)n;
    __syncthreads();
    for (int i = beg + t; i < end; i += 256) {
        unsigned c = pc[i] & 127u;
        unsigned slot = atomicAdd(&cur[c], 1u);
        node_sorted[slot] = (int)pn[i];
    }
}

// ---- feature max: 4 rows/iter, float4 lanes; 4 waves/block ----
__global__ __launch_bounds__(256) void k_pool(const float* __restrict__ x,
                      const int* __restrict__ node_sorted, const unsigned* __restrict__ off,
                      float* __restrict__ out_x) {
    int wid  = threadIdx.x >> 6;
    int lane = threadIdx.x & 63;
    int s = blockIdx.x * 4 + wid;
    unsigned beg = off[s], end = off[s + 1];
    int g   = lane >> 4;            // row group 0..3
    int cl4 = (lane & 15) << 2;     // column base
    float mx = -INFINITY, my = -INFINITY, mz = -INFINITY, mw = -INFINITY;
    for (unsigned idx = beg + g; idx < end; idx += 4) {
        int nd = node_sorted[idx];
        const float4 v = *(const float4*)&x[(size_t)nd * F + cl4];
        mx = fmaxf(mx, v.x); my = fmaxf(my, v.y);
        mz = fmaxf(mz, v.z); mw = fmaxf(mw, v.w);
    }
    #pragma unroll
    for (int o = 16; o <= 32; o <<= 1) {
        mx = fmaxf(mx, __shfl_xor(mx, o));
        my = fmaxf(my, __shfl_xor(my, o));
        mz = fmaxf(mz, __shfl_xor(mz, o));
        mw = fmaxf(mw, __shfl_xor(mw, o));
    }
    if (g == 0) {
        float4 r = (end > beg) ? make_float4(mx, my, mz, mw)
                               : make_float4(0.f, 0.f, 0.f, 0.f);
        *(float4*)&out_x[(size_t)s * F + cl4] = r;
    }
}

// ---- edge keys + coarse histogram + fused max|cart| partials ----
__global__ __launch_bounds__(PTHR) void k_ehist(const int* __restrict__ ei, int e,
                        const int* __restrict__ cl, const float2* __restrict__ pos_pool,
                        unsigned* __restrict__ keysA, unsigned* __restrict__ etable,
                        float* __restrict__ pmax) {
    __shared__ unsigned hist[NBIN];
    __shared__ float shm[PTHR / 64];
    int t = threadIdx.x, b = blockIdx.x;
    for (int j = t; j < NBIN; j += PTHR) hist[j] = 0u;
    __syncthreads();
    float am = 0.f;
    for (int i = b * PTHR + t; i < e; i += GPART * PTHR) {
        unsigned r = (unsigned)cl[ei[i]];
        unsigned c = (unsigned)cl[ei[e + i]];
        unsigned k = (r << 16) | c;
        keysA[i] = k;
        atomicAdd(&hist[k >> BSH], 1u);
        if (r != c) {
            float2 pr = pos_pool[r], pcc = pos_pool[c];
            am = fmaxf(am, fmaxf(fabsf(pr.x - pcc.x), fabsf(pr.y - pcc.y)));
        }
    }
    __syncthreads();
    for (int j = t; j < NBIN; j += PTHR) etable[j * GPART + b] = hist[j];
    am = wave_max(am);
    if ((t & 63) == 0) shm[t >> 6] = am;
    __syncthreads();
    if (t == 0) {
        float m = shm[0];
        for (int i2 = 1; i2 < PTHR / 64; ++i2) m = fmaxf(m, shm[i2]);
        pmax[b] = m;
    }
}

// ---- coalesced coarse partition of edge keys (A -> B) ----
__global__ __launch_bounds__(PTHR) void k_partition(const unsigned* __restrict__ keysA, int e,
                            const unsigned* __restrict__ etable,
                            unsigned* __restrict__ keysB) {
    __shared__ unsigned stage[8192];
    __shared__ unsigned h[NBIN], cur[NBIN], tbl_s[NBIN];
    int t = threadIdx.x, b = blockIdx.x;
    h[t] = 0u;
    tbl_s[t] = etable[t * GPART + b];
    __syncthreads();
    for (int i = b * PTHR + t; i < e; i += GPART * PTHR)
        atomicAdd(&h[keysA[i] >> BSH], 1u);
    __syncthreads();
    unsigned v = h[t];
    cur[t] = v;
    __syncthreads();
    for (int s = 1; s < NBIN; s <<= 1) {
        unsigned u = (t >= s) ? cur[t - s] : 0u;
        __syncthreads();
        cur[t] += u;
        __syncthreads();
    }
    unsigned incl = cur[t];
    __syncthreads();
    cur[t] = incl - v;
    __syncthreads();
    for (int i = b * PTHR + t; i < e; i += GPART * PTHR) {
        unsigned k = keysA[i];
        unsigned p = atomicAdd(&cur[k >> BSH], 1u);
        stage[p] = k;
    }
    __syncthreads();
    int cnt = (int)cur[NBIN - 1];
    for (int j = t; j < cnt; j += PTHR) {
        unsigned k = stage[j];
        unsigned bin = k >> BSH;
        unsigned start = cur[bin] - h[bin];
        keysB[tbl_s[bin] + ((unsigned)j - start)] = k;
    }
}

// ---- 13-bit LDS counting sort per coarse bin + fused low-10-bit run-finish ----
__global__ __launch_bounds__(512) void k_subsort(const unsigned* __restrict__ src,
                         unsigned* __restrict__ dst, const unsigned* __restrict__ table) {
    __shared__ unsigned hist[8192];     // slot(d) = (d&15)*512 + (d>>4)
    __shared__ unsigned stage[SCAP];
    __shared__ unsigned ss[512];
    int b = blockIdx.x, t = threadIdx.x;
    int beg = (int)table[b * GPART];
    int end = (int)table[(b + 1) * GPART];   // b==NBIN-1 -> table[ETBL]==e
    int len = end - beg;
    if (len <= 0) return;
    for (int j = t; j < 8192; j += 512) hist[j] = 0u;
    __syncthreads();
    for (int i = beg + t; i < end; i += 512) {
        unsigned d = (src[i] >> 10) & 8191u;
        atomicAdd(&hist[((d & 15u) << 9) | (d >> 4)], 1u);
    }
    __syncthreads();
    unsigned loc[16];
    unsigned s = 0;
    #pragma unroll
    for (int u = 0; u < 16; ++u) { loc[u] = s; s += hist[u * 512 + t]; }
    ss[t] = s;
    __syncthreads();
    for (int st = 1; st < 512; st <<= 1) {
        unsigned u2 = (t >= st) ? ss[t - st] : 0u;
        __syncthreads();
        ss[t] += u2;
        __syncthreads();
    }
    bool inlds = (len <= SCAP);
    unsigned base0 = (inlds ? 0u : (unsigned)beg) + ss[t] - s;
    #pragma unroll
    for (int u = 0; u < 16; ++u) hist[u * 512 + t] = base0 + loc[u];
    __syncthreads();
    if (inlds) {
        for (int i = beg + t; i < end; i += 512) {
            unsigned k = src[i];
            unsigned d = (k >> 10) & 8191u;
            stage[atomicAdd(&hist[((d & 15u) << 9) | (d >> 4)], 1u)] = k;
        }
        __syncthreads();
        // run-finish: runs = equal top-22 bits (never cross bins); sort low 10 bits
        for (int j = t; j < len; j += 512) {
            unsigned hi = stage[j] >> 10;
            if (j > 0 && (stage[j - 1] >> 10) == hi) continue;
            int rend = j + 1;
            while (rend < len && (stage[rend] >> 10) == hi) ++rend;
            for (int a = j + 1; a < rend; ++a) {
                unsigned v = stage[a]; int c = a - 1;
                while (c >= j && stage[c] > v) { stage[c + 1] = stage[c]; --c; }
                stage[c + 1] = v;
            }
        }
        __syncthreads();
        for (int j = t; j < len; j += 512) dst[beg + j] = stage[j];
    } else {
        // 27-sigma-unreachable fallback: scatter + run-finish in global
        for (int i = beg + t; i < end; i += 512) {
            unsigned k = src[i];
            unsigned d = (k >> 10) & 8191u;
            dst[atomicAdd(&hist[((d & 15u) << 9) | (d >> 4)], 1u)] = k;
        }
        __threadfence();
        __syncthreads();
        for (int j = beg + t; j < end; j += 512) {
            unsigned hi = dst[j] >> 10;
            if (j > beg && (dst[j - 1] >> 10) == hi) continue;
            int rend = j + 1;
            while (rend < end && (dst[rend] >> 10) == hi) ++rend;
            for (int a = j + 1; a < rend; ++a) {
                unsigned v = dst[a]; int c = a - 1;
                while (c >= j && dst[c] > v) { dst[c + 1] = dst[c]; --c; }
                dst[c + 1] = v;
            }
        }
    }
}

// ---- final edge outputs; per-block reduction of pmax partials (no sync kernel) ----
__global__ __launch_bounds__(256) void k_eflags(const unsigned* __restrict__ keys, int e,
                         const float2* __restrict__ pos_pool, const float* __restrict__ pmax,
                         float* __restrict__ out_erow, float* __restrict__ out_ecol,
                         float* __restrict__ out_valid, float2* __restrict__ out_attr) {
    __shared__ float shm[4];
    int t = threadIdx.x;
    float m = fmaxf(pmax[t], pmax[t + 256]);
    m = wave_max(m);
    if ((t & 63) == 0) shm[t >> 6] = m;
    __syncthreads();
    float denom = 2.0f * fmaxf(fmaxf(shm[0], shm[1]), fmaxf(shm[2], shm[3]));
    int i = blockIdx.x * blockDim.x + t;
    if (i >= e) return;
    unsigned k = keys[i];
    bool first = (i == 0) || (k != keys[i - 1]);
    unsigned r = k >> 16, c = k & 0xFFFFu;
    bool valid = first && (r != c);
    float ax = 0.f, ay = 0.f;
    if (valid) {
        float2 pr = pos_pool[r], pcc = pos_pool[c];
        ax = (pr.x - pcc.x) / denom + 0.5f;
        ay = (pr.y - pcc.y) / denom + 0.5f;
    }
    out_erow[i]  = valid ? (float)r : 0.f;
    out_ecol[i]  = valid ? (float)c : 0.f;
    out_valid[i] = valid ? 1.f : 0.f;
    out_attr[i]  = make_float2(ax, ay);
}

extern "C" void kernel_launch(void* const* d_in, const int* in_sizes, int n_in,
                              void* d_out, int out_size, void* d_ws, size_t ws_size,
                              hipStream_t stream) {
    const float* x    = (const float*)d_in[0];
    const float* pos  = (const float*)d_in[1];
    const int* batch  = (const int*)d_in[2];
    const int* ei     = (const int*)d_in[3];
    const int n = in_sizes[2];
    const int e = in_sizes[3] / 2;

    float* out      = (float*)d_out;
    float* out_x    = out;                                   // [SEG, F]
    float* out_pos  = out_x  + (size_t)SEG * F;              // [SEG, 2]
    float* out_erow = out_pos + (size_t)SEG * 2;             // [E]
    float* out_ecol = out_erow + e;                          // [E]
    float* out_attr = out_ecol + e;                          // [E, 2]
    float* out_val  = out_attr + (size_t)2 * e;              // [E]

    const int nb_e = (e + 255) / 256;

    char* w = (char*)d_ws;
    unsigned* hdr         = (unsigned*)w;                            // 2 u32 (pad 256)
    int*      cl          = (int*)(w + 256);                         // [n]
    int*      node_sorted = (int*)(w + 256 + (size_t)n * 4);         // [n]
    unsigned* node_off    = (unsigned*)(w + 256 + (size_t)n * 8);    // [SEG+1]
    unsigned* table       = node_off + SEG + 1;                      // [ETBL+1] (ntable alias)
    unsigned* keysA       = table + ETBL + 1;                        // [e] (alias: pc)
    unsigned* keysB       = keysA + e;                               // [e] (alias: pn)
    float2*   ppos        = (float2*)(keysB + e);                    // [n]
    unsigned* blksum      = (unsigned*)(ppos + n);                   // [256]
    float2*   pmin        = (float2*)(blksum + 256);                 // [MINB]
    float*    pmax        = (float*)(pmin + MINB);                   // [GPART]
    unsigned* ntable      = table;                                   // lifetime-disjoint alias
    unsigned* pc          = keysA;
    unsigned* pn          = keysB;

    // node side
    k_min<<<MINB, 256, 0, stream>>>((const float2*)pos, n, pmin);
    k_minred<<<1, 1024, 0, stream>>>(pmin, MINB, hdr);
    k_cluster<<<NGP, NTH, 0, stream>>>((const float2*)pos, batch, n, hdr, cl, ntable);
    k_scan1<<<NTBL / 1024, 1024, 0, stream>>>(ntable, ntable, blksum);
    k_scan_add<<<NTBL / 1024, 1024, 0, stream>>>(ntable, blksum, NTBL / 1024, NTBL, (unsigned)n);
    k_npart<<<NGP, NTH, 0, stream>>>(cl, (const float2*)pos, n, ntable, pc, pn, ppos);
    k_ngroup<<<NBIN, 256, 0, stream>>>(pc, pn, ppos, ntable, n, node_off, node_sorted,
                                       (float2*)out_pos);
    k_pool<<<SEG / 4, 256, 0, stream>>>(x, node_sorted, node_off, out_x);
    // edge side
    k_ehist<<<GPART, PTHR, 0, stream>>>(ei, e, cl, (const float2*)out_pos, keysA, table, pmax);
    k_scan1<<<ETBL / 1024, 1024, 0, stream>>>(table, table, blksum);
    k_scan_add<<<ETBL / 1024, 1024, 0, stream>>>(table, blksum, ETBL / 1024, ETBL, (unsigned)e);
    k_partition<<<GPART, PTHR, 0, stream>>>(keysA, e, table, keysB);
    k_subsort<<<NBIN, 512, 0, stream>>>(keysB, keysA, table);
    k_eflags<<<nb_e, 256, 0, stream>>>(keysA, e, (const float2*)out_pos, pmax,
                                       out_erow, out_ecol, out_val, (float2*)out_attr);
}

// Round 7
// 246.942 us; speedup vs baseline: 33579.9035x; 1.2657x over previous
//
#include <hip/hip_runtime.h>
#include <math.h>

static constexpr int F     = 64;
static constexpr int GRIDV = 64;
static constexpr int SEG   = 16 * GRIDV * GRIDV;   // 65536 clusters
static constexpr int MINB  = 1024;                 // blocks for k_min
// edge pipeline
static constexpr int GPART = 512;                  // blocks for edge hist/partition
static constexpr int PTHR  = 512;                  // threads for edge hist/partition
static constexpr int NBIN  = 512;                  // coarse bins (top 9 bits)
static constexpr int BSH   = 23;                   // key >> 23 -> coarse bin
static constexpr int ETBL  = NBIN * GPART;         // 262144
static constexpr int SCAP  = 10240;                // subsort LDS staging cap (+27 sigma)
// node pipeline
static constexpr int NGP   = 512;                  // blocks for node partition
static constexpr int NTH   = 256;                  // threads for node partition
static constexpr int NTBL  = NBIN * NGP;           // 262144

typedef float __attribute__((ext_vector_type(4))) f32x4;

__device__ __forceinline__ float wave_min(float v) {
    for (int o = 32; o > 0; o >>= 1) v = fminf(v, __shfl_down(v, o));
    return v;
}
__device__ __forceinline__ float wave_max(float v) {
    for (int o = 32; o > 0; o >>= 1) v = fmaxf(v, __shfl_down(v, o));
    return v;
}
__device__ __forceinline__ f32x4 vmax4(f32x4 a, f32x4 b) {
    f32x4 r;
    r.x = fmaxf(a.x, b.x); r.y = fmaxf(a.y, b.y);
    r.z = fmaxf(a.z, b.z); r.w = fmaxf(a.w, b.w);
    return r;
}

// ---- per-block partial min of pos ----
__global__ void k_min(const float2* __restrict__ pos, int n, float2* __restrict__ pmin) {
    __shared__ float shx[4], shy[4];
    int stride = gridDim.x * blockDim.x;
    float mx = INFINITY, my = INFINITY;
    for (int i = blockIdx.x * blockDim.x + threadIdx.x; i < n; i += stride) {
        float2 p = pos[i];
        mx = fminf(mx, p.x); my = fminf(my, p.y);
    }
    mx = wave_min(mx); my = wave_min(my);
    int w = threadIdx.x >> 6;
    if ((threadIdx.x & 63) == 0) { shx[w] = mx; shy[w] = my; }
    __syncthreads();
    if (threadIdx.x == 0) {
        mx = fminf(fminf(shx[0], shx[1]), fminf(shx[2], shx[3]));
        my = fminf(fminf(shy[0], shy[1]), fminf(shy[2], shy[3]));
        pmin[blockIdx.x] = make_float2(mx, my);
    }
}

__global__ void k_minred(const float2* __restrict__ pmin, int nb, unsigned* hdr) {
    __shared__ float shx[16], shy[16];
    int t = threadIdx.x;
    float mx = INFINITY, my = INFINITY;
    for (int i = t; i < nb; i += blockDim.x) {
        float2 p = pmin[i];
        mx = fminf(mx, p.x); my = fminf(my, p.y);
    }
    mx = wave_min(mx); my = wave_min(my);
    int w = t >> 6;
    if ((t & 63) == 0) { shx[w] = mx; shy[w] = my; }
    __syncthreads();
    if (t == 0) {
        int nw = (blockDim.x + 63) >> 6;
        for (int i = 1; i < nw; ++i) { mx = fminf(mx, shx[i]); my = fminf(my, shy[i]); }
        hdr[0] = (unsigned)__float_as_int(mx);
        hdr[1] = (unsigned)__float_as_int(my);
    }
}

// ---- cluster ids + coarse 512-bin per-block table (no global atomics) ----
__global__ __launch_bounds__(NTH) void k_cluster(const float2* __restrict__ pos,
                          const int* __restrict__ batch, int n,
                          const unsigned* __restrict__ hdr, int* __restrict__ cl,
                          unsigned* __restrict__ ntable) {
    __shared__ unsigned hist[NBIN];
    int t = threadIdx.x, b = blockIdx.x;
    for (int j = t; j < NBIN; j += NTH) hist[j] = 0u;
    __syncthreads();
    float sx = __int_as_float((int)hdr[0]);
    float sy = __int_as_float((int)hdr[1]);
    for (int i = b * NTH + t; i < n; i += NGP * NTH) {
        float2 p = pos[i];
        int vx = min(max((int)floorf((p.x - sx) * 64.0f), 0), GRIDV - 1);
        int vy = min(max((int)floorf((p.y - sy) * 64.0f), 0), GRIDV - 1);
        int c = batch[i] * (GRIDV * GRIDV) + vy * GRIDV + vx;
        cl[i] = c;
        atomicAdd(&hist[(unsigned)c >> 7], 1u);
    }
    __syncthreads();
    for (int j = t; j < NBIN; j += NTH) ntable[j * NGP + b] = hist[j];
}

// ---- hierarchical exclusive scan: stage 1 ----
__global__ void k_scan1(const unsigned* __restrict__ cnt, unsigned* __restrict__ off,
                        unsigned* __restrict__ blksum) {
    __shared__ unsigned sh[1024];
    int t = threadIdx.x;
    int g = blockIdx.x * 1024 + t;
    unsigned v = cnt[g];
    sh[t] = v;
    __syncthreads();
    for (int s = 1; s < 1024; s <<= 1) {
        unsigned u = (t >= s) ? sh[t - s] : 0u;
        __syncthreads();
        sh[t] += u;
        __syncthreads();
    }
    off[g] = sh[t] - v;
    if (t == 1023) blksum[blockIdx.x] = sh[1023];
}

// stage 2: add block bases; up to 256 stage-1 blocks
__global__ void k_scan_add(unsigned* __restrict__ off, const unsigned* __restrict__ blksum,
                           int nblk, int n, unsigned total) {
    __shared__ unsigned sh[256];
    int t = threadIdx.x, b = blockIdx.x;
    if (t < 256) sh[t] = (t < b && t < nblk) ? blksum[t] : 0u;
    __syncthreads();
    for (int s = 128; s > 0; s >>= 1) {
        if (t < s) sh[t] += sh[t + s];
        __syncthreads();
    }
    off[b * 1024 + t] += sh[0];
    if (b == 0 && t == 0) off[n] = total;
}

// ---- node coarse partition: (cluster,node,pos) staged in LDS, coalesced runs out ----
__global__ __launch_bounds__(NTH) void k_npart(const int* __restrict__ cl,
                       const float2* __restrict__ pos, int n,
                       const unsigned* __restrict__ ntable,
                       unsigned* __restrict__ pc, unsigned* __restrict__ pn,
                       float2* __restrict__ ppos) {
    __shared__ unsigned stage_c[2048], stage_n[2048];
    __shared__ float stage_px[2048], stage_py[2048];
    __shared__ unsigned h[NBIN], cur[NBIN], tbl_s[NBIN];
    __shared__ unsigned ss[NTH];
    int t = threadIdx.x, b = blockIdx.x;
    for (int j = t; j < NBIN; j += NTH) { h[j] = 0u; tbl_s[j] = ntable[j * NGP + b]; }
    __syncthreads();
    for (int i = b * NTH + t; i < n; i += NGP * NTH)
        atomicAdd(&h[((unsigned)cl[i]) >> 7], 1u);
    __syncthreads();
    unsigned a0 = h[2 * t], a1 = h[2 * t + 1];
    ss[t] = a0 + a1;
    __syncthreads();
    for (int s = 1; s < NTH; s <<= 1) {
        unsigned u = (t >= s) ? ss[t - s] : 0u;
        __syncthreads();
        ss[t] += u;
        __syncthreads();
    }
    unsigned base = ss[t] - (a0 + a1);
    cur[2 * t] = base;
    cur[2 * t + 1] = base + a0;
    __syncthreads();
    for (int i = b * NTH + t; i < n; i += NGP * NTH) {
        unsigned c = (unsigned)cl[i];
        float2 p = pos[i];
        unsigned q = atomicAdd(&cur[c >> 7], 1u);
        stage_c[q] = c; stage_n[q] = (unsigned)i;
        stage_px[q] = p.x; stage_py[q] = p.y;
    }
    __syncthreads();
    int cnt = (int)ss[NTH - 1];
    for (int j = t; j < cnt; j += NTH) {
        unsigned c = stage_c[j];
        unsigned bin = c >> 7;
        unsigned start = cur[bin] - h[bin];
        unsigned g = tbl_s[bin] + ((unsigned)j - start);
        pc[g] = c; pn[g] = stage_n[j];
        ppos[g] = make_float2(stage_px[j], stage_py[j]);
    }
}

// ---- per coarse bin: derive node_off, pos means, grouped node order ----
__global__ __launch_bounds__(256) void k_ngroup(const unsigned* __restrict__ pc,
                         const unsigned* __restrict__ pn, const float2* __restrict__ ppos,
                         const unsigned* __restrict__ ntable, int n,
                         unsigned* __restrict__ node_off, int* __restrict__ node_sorted,
                         float2* __restrict__ out_pos) {
    __shared__ unsigned cnt[128], sc[128], cur[128];
    __shared__ float psx[128], psy[128];
    int b = blockIdx.x, t = threadIdx.x;
    if (t < 128) { cnt[t] = 0u; psx[t] = 0.f; psy[t] = 0.f; }
    __syncthreads();
    int beg = (int)ntable[b * NGP];
    int end = (int)ntable[(b + 1) * NGP];
    for (int i = beg + t; i < end; i += 256) {
        unsigned c = pc[i] & 127u;
        float2 p = ppos[i];
        atomicAdd(&cnt[c], 1u);
        atomicAdd(&psx[c], p.x);
        atomicAdd(&psy[c], p.y);
    }
    __syncthreads();
    if (t < 128) sc[t] = cnt[t];
    __syncthreads();
    for (int s = 1; s < 128; s <<= 1) {
        unsigned u = (t >= s && t < 128) ? sc[t - s] : 0u;
        __syncthreads();
        if (t < 128) sc[t] += u;
        __syncthreads();
    }
    if (t < 128) {
        unsigned basec = (unsigned)beg + sc[t] - cnt[t];
        node_off[b * 128 + t] = basec;
        cur[t] = basec;
        unsigned c2 = cnt[t];
        out_pos[b * 128 + t] = c2 ? make_float2(psx[t] / (float)c2, psy[t] / (float)c2)
                                  : make_float2(0.f, 0.f);
    }
    if (b == NBIN - 1 && t == 0) node_off[SEG] = (unsigned)n;
    __syncthreads();
    for (int i = beg + t; i < end; i += 256) {
        unsigned c = pc[i] & 127u;
        unsigned slot = atomicAdd(&cur[c], 1u);
        node_sorted[slot] = (int)pn[i];
    }
}

// ---- feature max: wave-coalesced node-id load + shfl broadcast, 2x unrolled float4 ----
__global__ __launch_bounds__(256) void k_pool(const float* __restrict__ x,
                      const int* __restrict__ node_sorted, const unsigned* __restrict__ off,
                      float* __restrict__ out_x) {
    int wid  = threadIdx.x >> 6;
    int lane = threadIdx.x & 63;
    int s = blockIdx.x * 4 + wid;
    unsigned beg = off[s], end = off[s + 1];
    int g   = lane >> 4;            // row group 0..3
    int cl4 = (lane & 15) << 2;     // column base
    f32x4 m0, m1;
    m0.x = m0.y = m0.z = m0.w = -INFINITY;
    m1 = m0;
    for (unsigned base = beg; base < end; base += 64) {
        int nd_my = (base + (unsigned)lane < end) ? node_sorted[base + lane] : 0;
        int m = (int)min(64u, end - base);
        int j = g;
        for (; j + 4 < m; j += 8) {
            int nd0 = __shfl(nd_my, j);
            int nd1 = __shfl(nd_my, j + 4);
            f32x4 v0 = __builtin_nontemporal_load((const f32x4*)&x[(size_t)nd0 * F + cl4]);
            f32x4 v1 = __builtin_nontemporal_load((const f32x4*)&x[(size_t)nd1 * F + cl4]);
            m0 = vmax4(m0, v0);
            m1 = vmax4(m1, v1);
        }
        if (j < m) {
            int nd0 = __shfl(nd_my, j);
            f32x4 v0 = __builtin_nontemporal_load((const f32x4*)&x[(size_t)nd0 * F + cl4]);
            m0 = vmax4(m0, v0);
        }
    }
    m0 = vmax4(m0, m1);
    #pragma unroll
    for (int o = 16; o <= 32; o <<= 1) {
        m0.x = fmaxf(m0.x, __shfl_xor(m0.x, o));
        m0.y = fmaxf(m0.y, __shfl_xor(m0.y, o));
        m0.z = fmaxf(m0.z, __shfl_xor(m0.z, o));
        m0.w = fmaxf(m0.w, __shfl_xor(m0.w, o));
    }
    if (g == 0) {
        f32x4 r;
        if (end > beg) r = m0;
        else { r.x = r.y = r.z = r.w = 0.f; }
        *(f32x4*)&out_x[(size_t)s * F + cl4] = r;
    }
}

// ---- edge keys + coarse histogram (pure; no gathers beyond cl) ----
__global__ __launch_bounds__(PTHR) void k_ehist(const int* __restrict__ ei, int e,
                        const int* __restrict__ cl,
                        unsigned* __restrict__ keysA, unsigned* __restrict__ etable) {
    __shared__ unsigned hist[NBIN];
    int t = threadIdx.x, b = blockIdx.x;
    for (int j = t; j < NBIN; j += PTHR) hist[j] = 0u;
    __syncthreads();
    for (int i = b * PTHR + t; i < e; i += GPART * PTHR) {
        unsigned r = (unsigned)cl[ei[i]];
        unsigned c = (unsigned)cl[ei[e + i]];
        unsigned k = (r << 16) | c;
        keysA[i] = k;
        atomicAdd(&hist[k >> BSH], 1u);
    }
    __syncthreads();
    for (int j = t; j < NBIN; j += PTHR) etable[j * GPART + b] = hist[j];
}

// ---- coalesced coarse partition of edge keys (A -> B) ----
__global__ __launch_bounds__(PTHR) void k_partition(const unsigned* __restrict__ keysA, int e,
                            const unsigned* __restrict__ etable,
                            unsigned* __restrict__ keysB) {
    __shared__ unsigned stage[8192];
    __shared__ unsigned h[NBIN], cur[NBIN], tbl_s[NBIN];
    int t = threadIdx.x, b = blockIdx.x;
    h[t] = 0u;
    tbl_s[t] = etable[t * GPART + b];
    __syncthreads();
    for (int i = b * PTHR + t; i < e; i += GPART * PTHR)
        atomicAdd(&h[keysA[i] >> BSH], 1u);
    __syncthreads();
    unsigned v = h[t];
    cur[t] = v;
    __syncthreads();
    for (int s = 1; s < NBIN; s <<= 1) {
        unsigned u = (t >= s) ? cur[t - s] : 0u;
        __syncthreads();
        cur[t] += u;
        __syncthreads();
    }
    unsigned incl = cur[t];
    __syncthreads();
    cur[t] = incl - v;
    __syncthreads();
    for (int i = b * PTHR + t; i < e; i += GPART * PTHR) {
        unsigned k = keysA[i];
        unsigned p = atomicAdd(&cur[k >> BSH], 1u);
        stage[p] = k;
    }
    __syncthreads();
    int cnt = (int)cur[NBIN - 1];
    for (int j = t; j < cnt; j += PTHR) {
        unsigned k = stage[j];
        unsigned bin = k >> BSH;
        unsigned start = cur[bin] - h[bin];
        keysB[tbl_s[bin] + ((unsigned)j - start)] = k;
    }
}

// ---- 13-bit LDS counting sort per coarse bin + run-finish + FINAL edge outputs ----
__global__ __launch_bounds__(512) void k_subsort(const unsigned* __restrict__ src,
                         unsigned* __restrict__ scratch, const unsigned* __restrict__ table,
                         const float2* __restrict__ pos_pool,
                         float* __restrict__ out_erow, float* __restrict__ out_ecol,
                         float* __restrict__ out_valid, float2* __restrict__ out_attr,
                         float* __restrict__ pmax) {
    __shared__ unsigned hist[8192];     // slot(d) = (d&15)*512 + (d>>4)
    __shared__ unsigned stage[SCAP];
    __shared__ unsigned ss[512];
    __shared__ float shm[8];
    int b = blockIdx.x, t = threadIdx.x;
    int beg = (int)table[b * GPART];
    int end = (int)table[(b + 1) * GPART];   // b==NBIN-1 -> table[ETBL]==e
    int len = end - beg;
    if (len <= 0) { if (t == 0) pmax[b] = 0.f; return; }
    for (int j = t; j < 8192; j += 512) hist[j] = 0u;
    __syncthreads();
    for (int i = beg + t; i < end; i += 512) {
        unsigned d = (src[i] >> 10) & 8191u;
        atomicAdd(&hist[((d & 15u) << 9) | (d >> 4)], 1u);
    }
    __syncthreads();
    unsigned loc[16];
    unsigned s = 0;
    #pragma unroll
    for (int u = 0; u < 16; ++u) { loc[u] = s; s += hist[u * 512 + t]; }
    ss[t] = s;
    __syncthreads();
    for (int st = 1; st < 512; st <<= 1) {
        unsigned u2 = (t >= st) ? ss[t - st] : 0u;
        __syncthreads();
        ss[t] += u2;
        __syncthreads();
    }
    bool inlds = (len <= SCAP);
    unsigned base0 = (inlds ? 0u : (unsigned)beg) + ss[t] - s;
    #pragma unroll
    for (int u = 0; u < 16; ++u) hist[u * 512 + t] = base0 + loc[u];
    __syncthreads();
    float am = 0.f;
    if (inlds) {
        for (int i = beg + t; i < end; i += 512) {
            unsigned k = src[i];
            unsigned d = (k >> 10) & 8191u;
            stage[atomicAdd(&hist[((d & 15u) << 9) | (d >> 4)], 1u)] = k;
        }
        __syncthreads();
        // run-finish: runs = equal top-22 bits (never cross bins); sort low 10 bits
        for (int j = t; j < len; j += 512) {
            unsigned hi = stage[j] >> 10;
            if (j > 0 && (stage[j - 1] >> 10) == hi) continue;
            int rend = j + 1;
            while (rend < len && (stage[rend] >> 10) == hi) ++rend;
            for (int a = j + 1; a < rend; ++a) {
                unsigned v = stage[a]; int c = a - 1;
                while (c >= j && stage[c] > v) { stage[c + 1] = stage[c]; --c; }
                stage[c + 1] = v;
            }
        }
        __syncthreads();
        for (int j = t; j < len; j += 512) {
            unsigned k = stage[j];
            bool first = (j == 0) || (stage[j - 1] != k);
            unsigned r = k >> 16, c = k & 0xFFFFu;
            bool valid = first && (r != c);
            float ax, ay;
            if (valid) {
                float2 pr = pos_pool[r], pcc = pos_pool[c];
                ax = pr.x - pcc.x; ay = pr.y - pcc.y;
                am = fmaxf(am, fmaxf(fabsf(ax), fabsf(ay)));
            } else {
                ax = __int_as_float(0x7FC00000); ay = 0.f;   // NaN sentinel
            }
            out_erow[beg + j]  = valid ? (float)r : 0.f;
            out_ecol[beg + j]  = valid ? (float)c : 0.f;
            out_valid[beg + j] = valid ? 1.f : 0.f;
            out_attr[beg + j]  = make_float2(ax, ay);
        }
    } else {
        // 27-sigma-unreachable fallback: scatter + run-finish in global scratch
        for (int i = beg + t; i < end; i += 512) {
            unsigned k = src[i];
            unsigned d = (k >> 10) & 8191u;
            scratch[atomicAdd(&hist[((d & 15u) << 9) | (d >> 4)], 1u)] = k;
        }
        __threadfence();
        __syncthreads();
        for (int j = beg + t; j < end; j += 512) {
            unsigned hi = scratch[j] >> 10;
            if (j > beg && (scratch[j - 1] >> 10) == hi) continue;
            int rend = j + 1;
            while (rend < end && (scratch[rend] >> 10) == hi) ++rend;
            for (int a = j + 1; a < rend; ++a) {
                unsigned v = scratch[a]; int c = a - 1;
                while (c >= j && scratch[c] > v) { scratch[c + 1] = scratch[c]; --c; }
                scratch[c + 1] = v;
            }
        }
        __threadfence();
        __syncthreads();
        for (int j = beg + t; j < end; j += 512) {
            unsigned k = scratch[j];
            bool first = (j == beg) || (scratch[j - 1] != k);
            unsigned r = k >> 16, c = k & 0xFFFFu;
            bool valid = first && (r != c);
            float ax, ay;
            if (valid) {
                float2 pr = pos_pool[r], pcc = pos_pool[c];
                ax = pr.x - pcc.x; ay = pr.y - pcc.y;
                am = fmaxf(am, fmaxf(fabsf(ax), fabsf(ay)));
            } else {
                ax = __int_as_float(0x7FC00000); ay = 0.f;
            }
            out_erow[j]  = valid ? (float)r : 0.f;
            out_ecol[j]  = valid ? (float)c : 0.f;
            out_valid[j] = valid ? 1.f : 0.f;
            out_attr[j]  = make_float2(ax, ay);
        }
    }
    am = wave_max(am);
    if ((t & 63) == 0) shm[t >> 6] = am;
    __syncthreads();
    if (t == 0) {
        float m = shm[0];
        #pragma unroll
        for (int i2 = 1; i2 < 8; ++i2) m = fmaxf(m, shm[i2]);
        pmax[b] = m;
    }
}

// ---- in-place rescale: attr = cart/(2*max) + 0.5 (NaN sentinel -> 0) ----
__global__ __launch_bounds__(256) void k_rescale(float2* __restrict__ out_attr, int e,
                                                 const float* __restrict__ pmax) {
    __shared__ float shm[4];
    int t = threadIdx.x;
    float m = fmaxf(pmax[t], pmax[t + 256]);
    m = wave_max(m);
    if ((t & 63) == 0) shm[t >> 6] = m;
    __syncthreads();
    float denom = 2.0f * fmaxf(fmaxf(shm[0], shm[1]), fmaxf(shm[2], shm[3]));
    int i = blockIdx.x * blockDim.x + t;
    if (i >= e) return;
    float2 a = out_attr[i];
    bool valid = (a.x == a.x);
    float ax = valid ? a.x / denom + 0.5f : 0.f;
    float ay = valid ? a.y / denom + 0.5f : 0.f;
    out_attr[i] = make_float2(ax, ay);
}

extern "C" void kernel_launch(void* const* d_in, const int* in_sizes, int n_in,
                              void* d_out, int out_size, void* d_ws, size_t ws_size,
                              hipStream_t stream) {
    const float* x    = (const float*)d_in[0];
    const float* pos  = (const float*)d_in[1];
    const int* batch  = (const int*)d_in[2];
    const int* ei     = (const int*)d_in[3];
    const int n = in_sizes[2];
    const int e = in_sizes[3] / 2;

    float* out      = (float*)d_out;
    float* out_x    = out;                                   // [SEG, F]
    float* out_pos  = out_x  + (size_t)SEG * F;              // [SEG, 2]
    float* out_erow = out_pos + (size_t)SEG * 2;             // [E]
    float* out_ecol = out_erow + e;                          // [E]
    float* out_attr = out_ecol + e;                          // [E, 2]
    float* out_val  = out_attr + (size_t)2 * e;              // [E]

    const int nb_e = (e + 255) / 256;

    char* w = (char*)d_ws;
    unsigned* hdr         = (unsigned*)w;                            // 2 u32 (pad 256)
    int*      cl          = (int*)(w + 256);                         // [n]
    int*      node_sorted = (int*)(w + 256 + (size_t)n * 4);         // [n]
    unsigned* node_off    = (unsigned*)(w + 256 + (size_t)n * 8);    // [SEG+1]
    unsigned* table       = node_off + SEG + 1;                      // [ETBL+1] (ntable alias)
    unsigned* keysA       = table + ETBL + 1;                        // [e] (alias: pc)
    unsigned* keysB       = keysA + e;                               // [e] (alias: pn)
    float2*   ppos        = (float2*)(keysB + e);                    // [n]
    unsigned* blksum      = (unsigned*)(ppos + n);                   // [256]
    float2*   pmin        = (float2*)(blksum + 256);                 // [MINB]
    float*    pmax        = (float*)(pmin + MINB);                   // [NBIN]
    unsigned* ntable      = table;                                   // lifetime-disjoint alias
    unsigned* pc          = keysA;
    unsigned* pn          = keysB;

    // node side
    k_min<<<MINB, 256, 0, stream>>>((const float2*)pos, n, pmin);
    k_minred<<<1, 1024, 0, stream>>>(pmin, MINB, hdr);
    k_cluster<<<NGP, NTH, 0, stream>>>((const float2*)pos, batch, n, hdr, cl, ntable);
    k_scan1<<<NTBL / 1024, 1024, 0, stream>>>(ntable, ntable, blksum);
    k_scan_add<<<NTBL / 1024, 1024, 0, stream>>>(ntable, blksum, NTBL / 1024, NTBL, (unsigned)n);
    k_npart<<<NGP, NTH, 0, stream>>>(cl, (const float2*)pos, n, ntable, pc, pn, ppos);
    k_ngroup<<<NBIN, 256, 0, stream>>>(pc, pn, ppos, ntable, n, node_off, node_sorted,
                                       (float2*)out_pos);
    k_pool<<<SEG / 4, 256, 0, stream>>>(x, node_sorted, node_off, out_x);
    // edge side
    k_ehist<<<GPART, PTHR, 0, stream>>>(ei, e, cl, keysA, table);
    k_scan1<<<ETBL / 1024, 1024, 0, stream>>>(table, table, blksum);
    k_scan_add<<<ETBL / 1024, 1024, 0, stream>>>(table, blksum, ETBL / 1024, ETBL, (unsigned)e);
    k_partition<<<GPART, PTHR, 0, stream>>>(keysA, e, table, keysB);
    k_subsort<<<NBIN, 512, 0, stream>>>(keysB, keysA, table, (const float2*)out_pos,
                                        out_erow, out_ecol, out_val, (float2*)out_attr, pmax);
    k_rescale<<<nb_e, 256, 0, stream>>>((float2*)out_attr, e, pmax);
}

// Round 8
// 244.089 us; speedup vs baseline: 33972.3235x; 1.0117x over previous
//
#include <hip/hip_runtime.h>
#include <math.h>

static constexpr int F     = 64;
static constexpr int GRIDV = 64;
static constexpr int SEG   = 16 * GRIDV * GRIDV;   // 65536 clusters
static constexpr int MINB  = 1024;                 // blocks for k_min
// edge pipeline
static constexpr int GPART = 512;                  // blocks for edge hist/partition
static constexpr int PTHR  = 512;                  // threads for edge hist/partition
static constexpr int NBIN  = 512;                  // coarse bins (top 9 bits)
static constexpr int BSH   = 23;                   // key >> 23 -> coarse bin
static constexpr int ETBL  = NBIN * GPART;         // 262144
static constexpr int SCAP  = 10240;                // subsort LDS staging cap (+27 sigma)
// node pipeline
static constexpr int NGP   = 512;                  // blocks for node partition
static constexpr int NTH   = 256;                  // threads for node partition
static constexpr int NTBL  = NBIN * NGP;           // 262144

typedef float __attribute__((ext_vector_type(4))) f32x4;

__device__ __forceinline__ float wave_min(float v) {
    for (int o = 32; o > 0; o >>= 1) v = fminf(v, __shfl_down(v, o));
    return v;
}
__device__ __forceinline__ float wave_max(float v) {
    for (int o = 32; o > 0; o >>= 1) v = fmaxf(v, __shfl_down(v, o));
    return v;
}
__device__ __forceinline__ f32x4 vmax4(f32x4 a, f32x4 b) {
    f32x4 r;
    r.x = fmaxf(a.x, b.x); r.y = fmaxf(a.y, b.y);
    r.z = fmaxf(a.z, b.z); r.w = fmaxf(a.w, b.w);
    return r;
}

// ---- per-block partial min of pos ----
__global__ void k_min(const float2* __restrict__ pos, int n, float2* __restrict__ pmin) {
    __shared__ float shx[4], shy[4];
    int stride = gridDim.x * blockDim.x;
    float mx = INFINITY, my = INFINITY;
    for (int i = blockIdx.x * blockDim.x + threadIdx.x; i < n; i += stride) {
        float2 p = pos[i];
        mx = fminf(mx, p.x); my = fminf(my, p.y);
    }
    mx = wave_min(mx); my = wave_min(my);
    int w = threadIdx.x >> 6;
    if ((threadIdx.x & 63) == 0) { shx[w] = mx; shy[w] = my; }
    __syncthreads();
    if (threadIdx.x == 0) {
        mx = fminf(fminf(shx[0], shx[1]), fminf(shx[2], shx[3]));
        my = fminf(fminf(shy[0], shy[1]), fminf(shy[2], shy[3]));
        pmin[blockIdx.x] = make_float2(mx, my);
    }
}

__global__ void k_minred(const float2* __restrict__ pmin, int nb, unsigned* hdr) {
    __shared__ float shx[16], shy[16];
    int t = threadIdx.x;
    float mx = INFINITY, my = INFINITY;
    for (int i = t; i < nb; i += blockDim.x) {
        float2 p = pmin[i];
        mx = fminf(mx, p.x); my = fminf(my, p.y);
    }
    mx = wave_min(mx); my = wave_min(my);
    int w = t >> 6;
    if ((t & 63) == 0) { shx[w] = mx; shy[w] = my; }
    __syncthreads();
    if (t == 0) {
        int nw = (blockDim.x + 63) >> 6;
        for (int i = 1; i < nw; ++i) { mx = fminf(mx, shx[i]); my = fminf(my, shy[i]); }
        hdr[0] = (unsigned)__float_as_int(mx);
        hdr[1] = (unsigned)__float_as_int(my);
    }
}

// ---- cluster ids + coarse 512-bin per-block table (no global atomics) ----
__global__ __launch_bounds__(NTH) void k_cluster(const float2* __restrict__ pos,
                          const int* __restrict__ batch, int n,
                          const unsigned* __restrict__ hdr, int* __restrict__ cl,
                          unsigned* __restrict__ ntable) {
    __shared__ unsigned hist[NBIN];
    int t = threadIdx.x, b = blockIdx.x;
    for (int j = t; j < NBIN; j += NTH) hist[j] = 0u;
    __syncthreads();
    float sx = __int_as_float((int)hdr[0]);
    float sy = __int_as_float((int)hdr[1]);
    for (int i = b * NTH + t; i < n; i += NGP * NTH) {
        float2 p = pos[i];
        int vx = min(max((int)floorf((p.x - sx) * 64.0f), 0), GRIDV - 1);
        int vy = min(max((int)floorf((p.y - sy) * 64.0f), 0), GRIDV - 1);
        int c = batch[i] * (GRIDV * GRIDV) + vy * GRIDV + vx;
        cl[i] = c;
        atomicAdd(&hist[(unsigned)c >> 7], 1u);
    }
    __syncthreads();
    for (int j = t; j < NBIN; j += NTH) ntable[j * NGP + b] = hist[j];
}

// ---- hierarchical exclusive scan: stage 1 ----
__global__ void k_scan1(const unsigned* __restrict__ cnt, unsigned* __restrict__ off,
                        unsigned* __restrict__ blksum) {
    __shared__ unsigned sh[1024];
    int t = threadIdx.x;
    int g = blockIdx.x * 1024 + t;
    unsigned v = cnt[g];
    sh[t] = v;
    __syncthreads();
    for (int s = 1; s < 1024; s <<= 1) {
        unsigned u = (t >= s) ? sh[t - s] : 0u;
        __syncthreads();
        sh[t] += u;
        __syncthreads();
    }
    off[g] = sh[t] - v;
    if (t == 1023) blksum[blockIdx.x] = sh[1023];
}

// stage 2: add block bases; up to 256 stage-1 blocks
__global__ void k_scan_add(unsigned* __restrict__ off, const unsigned* __restrict__ blksum,
                           int nblk, int n, unsigned total) {
    __shared__ unsigned sh[256];
    int t = threadIdx.x, b = blockIdx.x;
    if (t < 256) sh[t] = (t < b && t < nblk) ? blksum[t] : 0u;
    __syncthreads();
    for (int s = 128; s > 0; s >>= 1) {
        if (t < s) sh[t] += sh[t + s];
        __syncthreads();
    }
    off[b * 1024 + t] += sh[0];
    if (b == 0 && t == 0) off[n] = total;
}

// ---- node coarse partition: (cluster,node,pos) staged in LDS, coalesced runs out ----
__global__ __launch_bounds__(NTH) void k_npart(const int* __restrict__ cl,
                       const float2* __restrict__ pos, int n,
                       const unsigned* __restrict__ ntable,
                       unsigned* __restrict__ pc, unsigned* __restrict__ pn,
                       float2* __restrict__ ppos) {
    __shared__ unsigned stage_c[2048], stage_n[2048];
    __shared__ float stage_px[2048], stage_py[2048];
    __shared__ unsigned h[NBIN], cur[NBIN], tbl_s[NBIN];
    __shared__ unsigned ss[NTH];
    int t = threadIdx.x, b = blockIdx.x;
    for (int j = t; j < NBIN; j += NTH) { h[j] = 0u; tbl_s[j] = ntable[j * NGP + b]; }
    __syncthreads();
    for (int i = b * NTH + t; i < n; i += NGP * NTH)
        atomicAdd(&h[((unsigned)cl[i]) >> 7], 1u);
    __syncthreads();
    unsigned a0 = h[2 * t], a1 = h[2 * t + 1];
    ss[t] = a0 + a1;
    __syncthreads();
    for (int s = 1; s < NTH; s <<= 1) {
        unsigned u = (t >= s) ? ss[t - s] : 0u;
        __syncthreads();
        ss[t] += u;
        __syncthreads();
    }
    unsigned base = ss[t] - (a0 + a1);
    cur[2 * t] = base;
    cur[2 * t + 1] = base + a0;
    __syncthreads();
    for (int i = b * NTH + t; i < n; i += NGP * NTH) {
        unsigned c = (unsigned)cl[i];
        float2 p = pos[i];
        unsigned q = atomicAdd(&cur[c >> 7], 1u);
        stage_c[q] = c; stage_n[q] = (unsigned)i;
        stage_px[q] = p.x; stage_py[q] = p.y;
    }
    __syncthreads();
    int cnt = (int)ss[NTH - 1];
    for (int j = t; j < cnt; j += NTH) {
        unsigned c = stage_c[j];
        unsigned bin = c >> 7;
        unsigned start = cur[bin] - h[bin];
        unsigned g = tbl_s[bin] + ((unsigned)j - start);
        pc[g] = c; pn[g] = stage_n[j];
        ppos[g] = make_float2(stage_px[j], stage_py[j]);
    }
}

// ---- per coarse bin: derive node_off, pos means, grouped node order ----
__global__ __launch_bounds__(256) void k_ngroup(const unsigned* __restrict__ pc,
                         const unsigned* __restrict__ pn, const float2* __restrict__ ppos,
                         const unsigned* __restrict__ ntable, int n,
                         unsigned* __restrict__ node_off, int* __restrict__ node_sorted,
                         float2* __restrict__ out_pos) {
    __shared__ unsigned cnt[128], sc[128], cur[128];
    __shared__ float psx[128], psy[128];
    int b = blockIdx.x, t = threadIdx.x;
    if (t < 128) { cnt[t] = 0u; psx[t] = 0.f; psy[t] = 0.f; }
    __syncthreads();
    int beg = (int)ntable[b * NGP];
    int end = (int)ntable[(b + 1) * NGP];
    for (int i = beg + t; i < end; i += 256) {
        unsigned c = pc[i] & 127u;
        float2 p = ppos[i];
        atomicAdd(&cnt[c], 1u);
        atomicAdd(&psx[c], p.x);
        atomicAdd(&psy[c], p.y);
    }
    __syncthreads();
    if (t < 128) sc[t] = cnt[t];
    __syncthreads();
    for (int s = 1; s < 128; s <<= 1) {
        unsigned u = (t >= s && t < 128) ? sc[t - s] : 0u;
        __syncthreads();
        if (t < 128) sc[t] += u;
        __syncthreads();
    }
    if (t < 128) {
        unsigned basec = (unsigned)beg + sc[t] - cnt[t];
        node_off[b * 128 + t] = basec;
        cur[t] = basec;
        unsigned c2 = cnt[t];
        out_pos[b * 128 + t] = c2 ? make_float2(psx[t] / (float)c2, psy[t] / (float)c2)
                                  : make_float2(0.f, 0.f);
    }
    if (b == NBIN - 1 && t == 0) node_off[SEG] = (unsigned)n;
    __syncthreads();
    for (int i = beg + t; i < end; i += 256) {
        unsigned c = pc[i] & 127u;
        unsigned slot = atomicAdd(&cur[c], 1u);
        node_sorted[slot] = (int)pn[i];
    }
}

// ---- feature max: wave-coalesced node-id load + shfl broadcast ----
// FIX vs prev round: row loop has a WAVE-UNIFORM trip count with CLAMPED row
// indices (idempotent for max). Divergent trip counts made __shfl read from
// EXEC=0 lanes, which returns 0 on CDNA (ds_bpermute) -> node 0 leaked in.
__global__ __launch_bounds__(256) void k_pool(const float* __restrict__ x,
                      const int* __restrict__ node_sorted, const unsigned* __restrict__ off,
                      float* __restrict__ out_x) {
    int wid  = threadIdx.x >> 6;
    int lane = threadIdx.x & 63;
    int s = blockIdx.x * 4 + wid;
    unsigned beg = off[s], end = off[s + 1];
    int g   = lane >> 4;            // row offset 0..3
    int cl4 = (lane & 15) << 2;     // column base
    f32x4 m0, m1, m2, m3;
    m0.x = m0.y = m0.z = m0.w = -INFINITY;
    m1 = m0; m2 = m0; m3 = m0;
    for (unsigned base = beg; base < end; base += 64) {
        int m = (int)min(64u, end - base);
        int nd_my = (lane < m) ? node_sorted[base + lane] : 0;
        int last = m - 1;
        int K = (m + 15) >> 4;                    // uniform across the wave
        for (int k = 0; k < K; ++k) {
            int j = g + (k << 4);
            int j0 = min(j, last);                // clamped: duplicate rows are
            int j1 = min(j + 4, last);            // idempotent under max
            int j2 = min(j + 8, last);
            int j3 = min(j + 12, last);
            int n0 = __shfl(nd_my, j0);
            int n1 = __shfl(nd_my, j1);
            int n2 = __shfl(nd_my, j2);
            int n3 = __shfl(nd_my, j3);
            f32x4 v0 = __builtin_nontemporal_load((const f32x4*)&x[(size_t)n0 * F + cl4]);
            f32x4 v1 = __builtin_nontemporal_load((const f32x4*)&x[(size_t)n1 * F + cl4]);
            f32x4 v2 = __builtin_nontemporal_load((const f32x4*)&x[(size_t)n2 * F + cl4]);
            f32x4 v3 = __builtin_nontemporal_load((const f32x4*)&x[(size_t)n3 * F + cl4]);
            m0 = vmax4(m0, v0);
            m1 = vmax4(m1, v1);
            m2 = vmax4(m2, v2);
            m3 = vmax4(m3, v3);
        }
    }
    m0 = vmax4(vmax4(m0, m1), vmax4(m2, m3));
    #pragma unroll
    for (int o = 16; o <= 32; o <<= 1) {
        m0.x = fmaxf(m0.x, __shfl_xor(m0.x, o));
        m0.y = fmaxf(m0.y, __shfl_xor(m0.y, o));
        m0.z = fmaxf(m0.z, __shfl_xor(m0.z, o));
        m0.w = fmaxf(m0.w, __shfl_xor(m0.w, o));
    }
    if (g == 0) {
        f32x4 r;
        if (end > beg) r = m0;
        else { r.x = r.y = r.z = r.w = 0.f; }
        *(f32x4*)&out_x[(size_t)s * F + cl4] = r;
    }
}

// ---- edge keys + coarse histogram (pure; no gathers beyond cl) ----
__global__ __launch_bounds__(PTHR) void k_ehist(const int* __restrict__ ei, int e,
                        const int* __restrict__ cl,
                        unsigned* __restrict__ keysA, unsigned* __restrict__ etable) {
    __shared__ unsigned hist[NBIN];
    int t = threadIdx.x, b = blockIdx.x;
    for (int j = t; j < NBIN; j += PTHR) hist[j] = 0u;
    __syncthreads();
    for (int i = b * PTHR + t; i < e; i += GPART * PTHR) {
        unsigned r = (unsigned)cl[ei[i]];
        unsigned c = (unsigned)cl[ei[e + i]];
        unsigned k = (r << 16) | c;
        keysA[i] = k;
        atomicAdd(&hist[k >> BSH], 1u);
    }
    __syncthreads();
    for (int j = t; j < NBIN; j += PTHR) etable[j * GPART + b] = hist[j];
}

// ---- coalesced coarse partition of edge keys (A -> B) ----
__global__ __launch_bounds__(PTHR) void k_partition(const unsigned* __restrict__ keysA, int e,
                            const unsigned* __restrict__ etable,
                            unsigned* __restrict__ keysB) {
    __shared__ unsigned stage[8192];
    __shared__ unsigned h[NBIN], cur[NBIN], tbl_s[NBIN];
    int t = threadIdx.x, b = blockIdx.x;
    h[t] = 0u;
    tbl_s[t] = etable[t * GPART + b];
    __syncthreads();
    for (int i = b * PTHR + t; i < e; i += GPART * PTHR)
        atomicAdd(&h[keysA[i] >> BSH], 1u);
    __syncthreads();
    unsigned v = h[t];
    cur[t] = v;
    __syncthreads();
    for (int s = 1; s < NBIN; s <<= 1) {
        unsigned u = (t >= s) ? cur[t - s] : 0u;
        __syncthreads();
        cur[t] += u;
        __syncthreads();
    }
    unsigned incl = cur[t];
    __syncthreads();
    cur[t] = incl - v;
    __syncthreads();
    for (int i = b * PTHR + t; i < e; i += GPART * PTHR) {
        unsigned k = keysA[i];
        unsigned p = atomicAdd(&cur[k >> BSH], 1u);
        stage[p] = k;
    }
    __syncthreads();
    int cnt = (int)cur[NBIN - 1];
    for (int j = t; j < cnt; j += PTHR) {
        unsigned k = stage[j];
        unsigned bin = k >> BSH;
        unsigned start = cur[bin] - h[bin];
        keysB[tbl_s[bin] + ((unsigned)j - start)] = k;
    }
}

// ---- 13-bit LDS counting sort per coarse bin + run-finish + FINAL edge outputs ----
__global__ __launch_bounds__(512) void k_subsort(const unsigned* __restrict__ src,
                         unsigned* __restrict__ scratch, const unsigned* __restrict__ table,
                         const float2* __restrict__ pos_pool,
                         float* __restrict__ out_erow, float* __restrict__ out_ecol,
                         float* __restrict__ out_valid, float2* __restrict__ out_attr,
                         float* __restrict__ pmax) {
    __shared__ unsigned hist[8192];     // slot(d) = (d&15)*512 + (d>>4)
    __shared__ unsigned stage[SCAP];
    __shared__ unsigned ss[512];
    __shared__ float shm[8];
    int b = blockIdx.x, t = threadIdx.x;
    int beg = (int)table[b * GPART];
    int end = (int)table[(b + 1) * GPART];   // b==NBIN-1 -> table[ETBL]==e
    int len = end - beg;
    if (len <= 0) { if (t == 0) pmax[b] = 0.f; return; }
    for (int j = t; j < 8192; j += 512) hist[j] = 0u;
    __syncthreads();
    for (int i = beg + t; i < end; i += 512) {
        unsigned d = (src[i] >> 10) & 8191u;
        atomicAdd(&hist[((d & 15u) << 9) | (d >> 4)], 1u);
    }
    __syncthreads();
    unsigned loc[16];
    unsigned s = 0;
    #pragma unroll
    for (int u = 0; u < 16; ++u) { loc[u] = s; s += hist[u * 512 + t]; }
    ss[t] = s;
    __syncthreads();
    for (int st = 1; st < 512; st <<= 1) {
        unsigned u2 = (t >= st) ? ss[t - st] : 0u;
        __syncthreads();
        ss[t] += u2;
        __syncthreads();
    }
    bool inlds = (len <= SCAP);
    unsigned base0 = (inlds ? 0u : (unsigned)beg) + ss[t] - s;
    #pragma unroll
    for (int u = 0; u < 16; ++u) hist[u * 512 + t] = base0 + loc[u];
    __syncthreads();
    float am = 0.f;
    if (inlds) {
        for (int i = beg + t; i < end; i += 512) {
            unsigned k = src[i];
            unsigned d = (k >> 10) & 8191u;
            stage[atomicAdd(&hist[((d & 15u) << 9) | (d >> 4)], 1u)] = k;
        }
        __syncthreads();
        // run-finish: runs = equal top-22 bits (never cross bins); sort low 10 bits
        for (int j = t; j < len; j += 512) {
            unsigned hi = stage[j] >> 10;
            if (j > 0 && (stage[j - 1] >> 10) == hi) continue;
            int rend = j + 1;
            while (rend < len && (stage[rend] >> 10) == hi) ++rend;
            for (int a = j + 1; a < rend; ++a) {
                unsigned v = stage[a]; int c = a - 1;
                while (c >= j && stage[c] > v) { stage[c + 1] = stage[c]; --c; }
                stage[c + 1] = v;
            }
        }
        __syncthreads();
        for (int j = t; j < len; j += 512) {
            unsigned k = stage[j];
            bool first = (j == 0) || (stage[j - 1] != k);
            unsigned r = k >> 16, c = k & 0xFFFFu;
            bool valid = first && (r != c);
            float ax, ay;
            if (valid) {
                float2 pr = pos_pool[r], pcc = pos_pool[c];
                ax = pr.x - pcc.x; ay = pr.y - pcc.y;
                am = fmaxf(am, fmaxf(fabsf(ax), fabsf(ay)));
            } else {
                ax = __int_as_float(0x7FC00000); ay = 0.f;   // NaN sentinel
            }
            out_erow[beg + j]  = valid ? (float)r : 0.f;
            out_ecol[beg + j]  = valid ? (float)c : 0.f;
            out_valid[beg + j] = valid ? 1.f : 0.f;
            out_attr[beg + j]  = make_float2(ax, ay);
        }
    } else {
        // 27-sigma-unreachable fallback: scatter + run-finish in global scratch
        for (int i = beg + t; i < end; i += 512) {
            unsigned k = src[i];
            unsigned d = (k >> 10) & 8191u;
            scratch[atomicAdd(&hist[((d & 15u) << 9) | (d >> 4)], 1u)] = k;
        }
        __threadfence();
        __syncthreads();
        for (int j = beg + t; j < end; j += 512) {
            unsigned hi = scratch[j] >> 10;
            if (j > beg && (scratch[j - 1] >> 10) == hi) continue;
            int rend = j + 1;
            while (rend < end && (scratch[rend] >> 10) == hi) ++rend;
            for (int a = j + 1; a < rend; ++a) {
                unsigned v = scratch[a]; int c = a - 1;
                while (c >= j && scratch[c] > v) { scratch[c + 1] = scratch[c]; --c; }
                scratch[c + 1] = v;
            }
        }
        __threadfence();
        __syncthreads();
        for (int j = beg + t; j < end; j += 512) {
            unsigned k = scratch[j];
            bool first = (j == beg) || (scratch[j - 1] != k);
            unsigned r = k >> 16, c = k & 0xFFFFu;
            bool valid = first && (r != c);
            float ax, ay;
            if (valid) {
                float2 pr = pos_pool[r], pcc = pos_pool[c];
                ax = pr.x - pcc.x; ay = pr.y - pcc.y;
                am = fmaxf(am, fmaxf(fabsf(ax), fabsf(ay)));
            } else {
                ax = __int_as_float(0x7FC00000); ay = 0.f;
            }
            out_erow[j]  = valid ? (float)r : 0.f;
            out_ecol[j]  = valid ? (float)c : 0.f;
            out_valid[j] = valid ? 1.f : 0.f;
            out_attr[j]  = make_float2(ax, ay);
        }
    }
    am = wave_max(am);
    if ((t & 63) == 0) shm[t >> 6] = am;
    __syncthreads();
    if (t == 0) {
        float m = shm[0];
        #pragma unroll
        for (int i2 = 1; i2 < 8; ++i2) m = fmaxf(m, shm[i2]);
        pmax[b] = m;
    }
}

// ---- in-place rescale: attr = cart/(2*max) + 0.5 (NaN sentinel -> 0) ----
__global__ __launch_bounds__(256) void k_rescale(float2* __restrict__ out_attr, int e,
                                                 const float* __restrict__ pmax) {
    __shared__ float shm[4];
    int t = threadIdx.x;
    float m = fmaxf(pmax[t], pmax[t + 256]);
    m = wave_max(m);
    if ((t & 63) == 0) shm[t >> 6] = m;
    __syncthreads();
    float denom = 2.0f * fmaxf(fmaxf(shm[0], shm[1]), fmaxf(shm[2], shm[3]));
    int i = blockIdx.x * blockDim.x + t;
    if (i >= e) return;
    float2 a = out_attr[i];
    bool valid = (a.x == a.x);
    float ax = valid ? a.x / denom + 0.5f : 0.f;
    float ay = valid ? a.y / denom + 0.5f : 0.f;
    out_attr[i] = make_float2(ax, ay);
}

extern "C" void kernel_launch(void* const* d_in, const int* in_sizes, int n_in,
                              void* d_out, int out_size, void* d_ws, size_t ws_size,
                              hipStream_t stream) {
    const float* x    = (const float*)d_in[0];
    const float* pos  = (const float*)d_in[1];
    const int* batch  = (const int*)d_in[2];
    const int* ei     = (const int*)d_in[3];
    const int n = in_sizes[2];
    const int e = in_sizes[3] / 2;

    float* out      = (float*)d_out;
    float* out_x    = out;                                   // [SEG, F]
    float* out_pos  = out_x  + (size_t)SEG * F;              // [SEG, 2]
    float* out_erow = out_pos + (size_t)SEG * 2;             // [E]
    float* out_ecol = out_erow + e;                          // [E]
    float* out_attr = out_ecol + e;                          // [E, 2]
    float* out_val  = out_attr + (size_t)2 * e;              // [E]

    const int nb_e = (e + 255) / 256;

    char* w = (char*)d_ws;
    unsigned* hdr         = (unsigned*)w;                            // 2 u32 (pad 256)
    int*      cl          = (int*)(w + 256);                         // [n]
    int*      node_sorted = (int*)(w + 256 + (size_t)n * 4);         // [n]
    unsigned* node_off    = (unsigned*)(w + 256 + (size_t)n * 8);    // [SEG+1]
    unsigned* table       = node_off + SEG + 1;                      // [ETBL+1] (ntable alias)
    unsigned* keysA       = table + ETBL + 1;                        // [e] (alias: pc)
    unsigned* keysB       = keysA + e;                               // [e] (alias: pn)
    float2*   ppos        = (float2*)(keysB + e);                    // [n]
    unsigned* blksum      = (unsigned*)(ppos + n);                   // [256]
    float2*   pmin        = (float2*)(blksum + 256);                 // [MINB]
    float*    pmax        = (float*)(pmin + MINB);                   // [NBIN]
    unsigned* ntable      = table;                                   // lifetime-disjoint alias
    unsigned* pc          = keysA;
    unsigned* pn          = keysB;

    // node side
    k_min<<<MINB, 256, 0, stream>>>((const float2*)pos, n, pmin);
    k_minred<<<1, 1024, 0, stream>>>(pmin, MINB, hdr);
    k_cluster<<<NGP, NTH, 0, stream>>>((const float2*)pos, batch, n, hdr, cl, ntable);
    k_scan1<<<NTBL / 1024, 1024, 0, stream>>>(ntable, ntable, blksum);
    k_scan_add<<<NTBL / 1024, 1024, 0, stream>>>(ntable, blksum, NTBL / 1024, NTBL, (unsigned)n);
    k_npart<<<NGP, NTH, 0, stream>>>(cl, (const float2*)pos, n, ntable, pc, pn, ppos);
    k_ngroup<<<NBIN, 256, 0, stream>>>(pc, pn, ppos, ntable, n, node_off, node_sorted,
                                       (float2*)out_pos);
    k_pool<<<SEG / 4, 256, 0, stream>>>(x, node_sorted, node_off, out_x);
    // edge side
    k_ehist<<<GPART, PTHR, 0, stream>>>(ei, e, cl, keysA, table);
    k_scan1<<<ETBL / 1024, 1024, 0, stream>>>(table, table, blksum);
    k_scan_add<<<ETBL / 1024, 1024, 0, stream>>>(table, blksum, ETBL / 1024, ETBL, (unsigned)e);
    k_partition<<<GPART, PTHR, 0, stream>>>(keysA, e, table, keysB);
    k_subsort<<<NBIN, 512, 0, stream>>>(keysB, keysA, table, (const float2*)out_pos,
                                        out_erow, out_ecol, out_val, (float2*)out_attr, pmax);
    k_rescale<<<nb_e, 256, 0, stream>>>((float2*)out_attr, e, pmax);
}

// Round 9
// 239.674 us; speedup vs baseline: 34598.2032x; 1.0184x over previous
//
#include <hip/hip_runtime.h>
#include <math.h>

static constexpr int F     = 64;
static constexpr int GRIDV = 64;
static constexpr int SEG   = 16 * GRIDV * GRIDV;   // 65536 clusters
static constexpr int MINB  = 256;                  // blocks for k_min
// edge pipeline
static constexpr int GPART = 512;                  // blocks for edge hist/partition
static constexpr int PTHR  = 512;                  // threads for edge hist/partition
static constexpr int NBIN  = 512;                  // coarse bins (top 9 bits)
static constexpr int BSH   = 23;                   // key >> 23 -> coarse bin
static constexpr int ETBL  = NBIN * GPART;         // 262144
static constexpr int SCAP  = 10240;                // subsort LDS staging cap (+27 sigma)
// node pipeline
static constexpr int NGP   = 512;                  // blocks for node partition
static constexpr int NTH   = 256;                  // threads for node partition
static constexpr int NTBL  = NBIN * NGP;           // 262144

typedef float __attribute__((ext_vector_type(4))) f32x4;

__device__ __forceinline__ float wave_min(float v) {
    for (int o = 32; o > 0; o >>= 1) v = fminf(v, __shfl_down(v, o));
    return v;
}
__device__ __forceinline__ float wave_max(float v) {
    for (int o = 32; o > 0; o >>= 1) v = fmaxf(v, __shfl_down(v, o));
    return v;
}
__device__ __forceinline__ f32x4 vmax4(f32x4 a, f32x4 b) {
    f32x4 r;
    r.x = fmaxf(a.x, b.x); r.y = fmaxf(a.y, b.y);
    r.z = fmaxf(a.z, b.z); r.w = fmaxf(a.w, b.w);
    return r;
}

// Block-wide inclusive scan, shfl-based (2 barriers). EXEC-mask safe: every
// shfl source lane is active (stage-2 sources are lanes < NT/64, all inside
// the same branch).
template <int NT>
__device__ __forceinline__ unsigned block_incl_scan(unsigned v, int t) {
    __shared__ unsigned wsum[NT / 64];
    int lane = t & 63, w = t >> 6;
    unsigned sc = v;
    #pragma unroll
    for (int o = 1; o < 64; o <<= 1) {
        unsigned u = __shfl_up(sc, o);
        if (lane >= o) sc += u;
    }
    if (lane == 63) wsum[w] = sc;
    __syncthreads();
    if (w == 0 && lane < NT / 64) {
        unsigned ws = wsum[lane];
        #pragma unroll
        for (int o = 1; o < NT / 64; o <<= 1) {
            unsigned u = __shfl_up(ws, o);
            if (lane >= o) ws += u;
        }
        wsum[lane] = ws;
    }
    __syncthreads();
    return sc + ((w > 0) ? wsum[w - 1] : 0u);
}

// ---- per-block partial min of pos ----
__global__ void k_min(const float2* __restrict__ pos, int n, float2* __restrict__ pmin) {
    __shared__ float shx[4], shy[4];
    int stride = gridDim.x * blockDim.x;
    float mx = INFINITY, my = INFINITY;
    for (int i = blockIdx.x * blockDim.x + threadIdx.x; i < n; i += stride) {
        float2 p = pos[i];
        mx = fminf(mx, p.x); my = fminf(my, p.y);
    }
    mx = wave_min(mx); my = wave_min(my);
    int w = threadIdx.x >> 6;
    if ((threadIdx.x & 63) == 0) { shx[w] = mx; shy[w] = my; }
    __syncthreads();
    if (threadIdx.x == 0) {
        mx = fminf(fminf(shx[0], shx[1]), fminf(shx[2], shx[3]));
        my = fminf(fminf(shy[0], shy[1]), fminf(shy[2], shy[3]));
        pmin[blockIdx.x] = make_float2(mx, my);
    }
}

__global__ void k_minred(const float2* __restrict__ pmin, int nb, unsigned* hdr) {
    __shared__ float shx[4], shy[4];
    int t = threadIdx.x;
    float mx = INFINITY, my = INFINITY;
    for (int i = t; i < nb; i += blockDim.x) {
        float2 p = pmin[i];
        mx = fminf(mx, p.x); my = fminf(my, p.y);
    }
    mx = wave_min(mx); my = wave_min(my);
    int w = t >> 6;
    if ((t & 63) == 0) { shx[w] = mx; shy[w] = my; }
    __syncthreads();
    if (t == 0) {
        int nw = (int)(blockDim.x + 63) >> 6;
        for (int i = 1; i < nw; ++i) { mx = fminf(mx, shx[i]); my = fminf(my, shy[i]); }
        hdr[0] = (unsigned)__float_as_int(mx);
        hdr[1] = (unsigned)__float_as_int(my);
    }
}

// ---- cluster ids + coarse 512-bin per-block table (no global atomics) ----
__global__ __launch_bounds__(NTH) void k_cluster(const float2* __restrict__ pos,
                          const int* __restrict__ batch, int n,
                          const unsigned* __restrict__ hdr, int* __restrict__ cl,
                          unsigned* __restrict__ ntable) {
    __shared__ unsigned hist[NBIN];
    int t = threadIdx.x, b = blockIdx.x;
    for (int j = t; j < NBIN; j += NTH) hist[j] = 0u;
    __syncthreads();
    float sx = __int_as_float((int)hdr[0]);
    float sy = __int_as_float((int)hdr[1]);
    for (int i = b * NTH + t; i < n; i += NGP * NTH) {
        float2 p = pos[i];
        int vx = min(max((int)floorf((p.x - sx) * 64.0f), 0), GRIDV - 1);
        int vy = min(max((int)floorf((p.y - sy) * 64.0f), 0), GRIDV - 1);
        int c = batch[i] * (GRIDV * GRIDV) + vy * GRIDV + vx;
        cl[i] = c;
        atomicAdd(&hist[(unsigned)c >> 7], 1u);
    }
    __syncthreads();
    for (int j = t; j < NBIN; j += NTH) ntable[j * NGP + b] = hist[j];
}

// ---- hierarchical exclusive scan: stage 1 (shfl-based, 2 barriers) ----
__global__ void k_scan1(const unsigned* __restrict__ cnt, unsigned* __restrict__ off,
                        unsigned* __restrict__ blksum) {
    int t = threadIdx.x;
    int g = blockIdx.x * 1024 + t;
    unsigned v = cnt[g];
    unsigned incl = block_incl_scan<1024>(v, t);
    off[g] = incl - v;
    if (t == 1023) blksum[blockIdx.x] = incl;
}

// stage 2: add block bases; up to 256 stage-1 blocks
__global__ void k_scan_add(unsigned* __restrict__ off, const unsigned* __restrict__ blksum,
                           int nblk, int n, unsigned total) {
    __shared__ unsigned sh[256];
    int t = threadIdx.x, b = blockIdx.x;
    if (t < 256) sh[t] = (t < b && t < nblk) ? blksum[t] : 0u;
    __syncthreads();
    for (int s = 128; s > 0; s >>= 1) {
        if (t < s) sh[t] += sh[t + s];
        __syncthreads();
    }
    off[b * 1024 + t] += sh[0];
    if (b == 0 && t == 0) off[n] = total;
}

// ---- node coarse partition; per-block counts from SCANNED-TABLE DIFFS ----
__global__ __launch_bounds__(NTH) void k_npart(const int* __restrict__ cl,
                       const float2* __restrict__ pos, int n,
                       const unsigned* __restrict__ ntable,
                       unsigned* __restrict__ pc, unsigned* __restrict__ pn,
                       float2* __restrict__ ppos) {
    __shared__ unsigned stage_c[2048], stage_n[2048];
    __shared__ float stage_px[2048], stage_py[2048];
    __shared__ unsigned h[NBIN], cur[NBIN], tbl_s[NBIN];
    int t = threadIdx.x, b = blockIdx.x;
    // h[bin] = diff of adjacent scanned entries (boundary ntable[NTBL] = n)
    for (int j = t; j < NBIN; j += NTH) {
        unsigned a = ntable[j * NGP + b];
        tbl_s[j] = a;
        h[j] = ntable[j * NGP + b + 1] - a;
    }
    __syncthreads();
    unsigned a0 = h[2 * t], a1 = h[2 * t + 1];
    unsigned incl = block_incl_scan<NTH>(a0 + a1, t);
    unsigned base = incl - (a0 + a1);
    cur[2 * t] = base;
    cur[2 * t + 1] = base + a0;
    __syncthreads();
    for (int i = b * NTH + t; i < n; i += NGP * NTH) {
        unsigned c = (unsigned)cl[i];
        float2 p = pos[i];
        unsigned q = atomicAdd(&cur[c >> 7], 1u);
        stage_c[q] = c; stage_n[q] = (unsigned)i;
        stage_px[q] = p.x; stage_py[q] = p.y;
    }
    __syncthreads();
    int cnt = (int)cur[NBIN - 1];          // = block total after placement
    for (int j = t; j < cnt; j += NTH) {
        unsigned c = stage_c[j];
        unsigned bin = c >> 7;
        unsigned start = cur[bin] - h[bin];
        unsigned g = tbl_s[bin] + ((unsigned)j - start);
        pc[g] = c; pn[g] = stage_n[j];
        ppos[g] = make_float2(stage_px[j], stage_py[j]);
    }
}

// ---- per coarse bin: derive node_off, pos means, grouped node order ----
__global__ __launch_bounds__(256) void k_ngroup(const unsigned* __restrict__ pc,
                         const unsigned* __restrict__ pn, const float2* __restrict__ ppos,
                         const unsigned* __restrict__ ntable, int n,
                         unsigned* __restrict__ node_off, int* __restrict__ node_sorted,
                         float2* __restrict__ out_pos) {
    __shared__ unsigned cnt[128], sc[128], cur[128];
    __shared__ float psx[128], psy[128];
    int b = blockIdx.x, t = threadIdx.x;
    if (t < 128) { cnt[t] = 0u; psx[t] = 0.f; psy[t] = 0.f; }
    __syncthreads();
    int beg = (int)ntable[b * NGP];
    int end = (int)ntable[(b + 1) * NGP];
    for (int i = beg + t; i < end; i += 256) {
        unsigned c = pc[i] & 127u;
        float2 p = ppos[i];
        atomicAdd(&cnt[c], 1u);
        atomicAdd(&psx[c], p.x);
        atomicAdd(&psy[c], p.y);
    }
    __syncthreads();
    if (t < 128) sc[t] = cnt[t];
    __syncthreads();
    for (int s = 1; s < 128; s <<= 1) {
        unsigned u = (t >= s && t < 128) ? sc[t - s] : 0u;
        __syncthreads();
        if (t < 128) sc[t] += u;
        __syncthreads();
    }
    if (t < 128) {
        unsigned basec = (unsigned)beg + sc[t] - cnt[t];
        node_off[b * 128 + t] = basec;
        cur[t] = basec;
        unsigned c2 = cnt[t];
        out_pos[b * 128 + t] = c2 ? make_float2(psx[t] / (float)c2, psy[t] / (float)c2)
                                  : make_float2(0.f, 0.f);
    }
    if (b == NBIN - 1 && t == 0) node_off[SEG] = (unsigned)n;
    __syncthreads();
    for (int i = beg + t; i < end; i += 256) {
        unsigned c = pc[i] & 127u;
        unsigned slot = atomicAdd(&cur[c], 1u);
        node_sorted[slot] = (int)pn[i];
    }
}

// ---- feature max: wave-coalesced node-id load + shfl broadcast ----
// Row loop: WAVE-UNIFORM trip count with CLAMPED row indices (idempotent for
// max). Divergent trips would make __shfl read EXEC=0 lanes -> 0 on CDNA.
__global__ __launch_bounds__(256) void k_pool(const float* __restrict__ x,
                      const int* __restrict__ node_sorted, const unsigned* __restrict__ off,
                      float* __restrict__ out_x) {
    int wid  = threadIdx.x >> 6;
    int lane = threadIdx.x & 63;
    int s = blockIdx.x * 4 + wid;
    unsigned beg = off[s], end = off[s + 1];
    int g   = lane >> 4;            // row offset 0..3
    int cl4 = (lane & 15) << 2;     // column base
    f32x4 m0, m1, m2, m3;
    m0.x = m0.y = m0.z = m0.w = -INFINITY;
    m1 = m0; m2 = m0; m3 = m0;
    for (unsigned base = beg; base < end; base += 64) {
        int m = (int)min(64u, end - base);
        int nd_my = (lane < m) ? node_sorted[base + lane] : 0;
        int last = m - 1;
        int K = (m + 15) >> 4;                    // uniform across the wave
        for (int k = 0; k < K; ++k) {
            int j = g + (k << 4);
            int j0 = min(j, last);
            int j1 = min(j + 4, last);
            int j2 = min(j + 8, last);
            int j3 = min(j + 12, last);
            int n0 = __shfl(nd_my, j0);
            int n1 = __shfl(nd_my, j1);
            int n2 = __shfl(nd_my, j2);
            int n3 = __shfl(nd_my, j3);
            f32x4 v0 = __builtin_nontemporal_load((const f32x4*)&x[(size_t)n0 * F + cl4]);
            f32x4 v1 = __builtin_nontemporal_load((const f32x4*)&x[(size_t)n1 * F + cl4]);
            f32x4 v2 = __builtin_nontemporal_load((const f32x4*)&x[(size_t)n2 * F + cl4]);
            f32x4 v3 = __builtin_nontemporal_load((const f32x4*)&x[(size_t)n3 * F + cl4]);
            m0 = vmax4(m0, v0);
            m1 = vmax4(m1, v1);
            m2 = vmax4(m2, v2);
            m3 = vmax4(m3, v3);
        }
    }
    m0 = vmax4(vmax4(m0, m1), vmax4(m2, m3));
    #pragma unroll
    for (int o = 16; o <= 32; o <<= 1) {
        m0.x = fmaxf(m0.x, __shfl_xor(m0.x, o));
        m0.y = fmaxf(m0.y, __shfl_xor(m0.y, o));
        m0.z = fmaxf(m0.z, __shfl_xor(m0.z, o));
        m0.w = fmaxf(m0.w, __shfl_xor(m0.w, o));
    }
    if (g == 0) {
        f32x4 r;
        if (end > beg) r = m0;
        else { r.x = r.y = r.z = r.w = 0.f; }
        *(f32x4*)&out_x[(size_t)s * F + cl4] = r;
    }
}

// ---- edge keys + coarse histogram ----
__global__ __launch_bounds__(PTHR) void k_ehist(const int* __restrict__ ei, int e,
                        const int* __restrict__ cl,
                        unsigned* __restrict__ keysA, unsigned* __restrict__ etable) {
    __shared__ unsigned hist[NBIN];
    int t = threadIdx.x, b = blockIdx.x;
    for (int j = t; j < NBIN; j += PTHR) hist[j] = 0u;
    __syncthreads();
    for (int i = b * PTHR + t; i < e; i += GPART * PTHR) {
        unsigned r = (unsigned)cl[ei[i]];
        unsigned c = (unsigned)cl[ei[e + i]];
        unsigned k = (r << 16) | c;
        keysA[i] = k;
        atomicAdd(&hist[k >> BSH], 1u);
    }
    __syncthreads();
    for (int j = t; j < NBIN; j += PTHR) etable[j * GPART + b] = hist[j];
}

// ---- coalesced coarse partition (A -> B); counts from SCANNED-TABLE DIFFS ----
__global__ __launch_bounds__(PTHR) void k_partition(const unsigned* __restrict__ keysA, int e,
                            const unsigned* __restrict__ etable,
                            unsigned* __restrict__ keysB) {
    __shared__ unsigned stage[8192];
    __shared__ unsigned h[NBIN], cur[NBIN], tbl_s[NBIN];
    int t = threadIdx.x, b = blockIdx.x;
    unsigned a = etable[t * GPART + b];            // boundary etable[ETBL] = e
    unsigned hv = etable[t * GPART + b + 1] - a;
    tbl_s[t] = a;
    h[t] = hv;
    __syncthreads();
    unsigned incl = block_incl_scan<PTHR>(hv, t);
    cur[t] = incl - hv;
    __syncthreads();
    for (int i = b * PTHR + t; i < e; i += GPART * PTHR) {
        unsigned k = keysA[i];
        unsigned p = atomicAdd(&cur[k >> BSH], 1u);
        stage[p] = k;
    }
    __syncthreads();
    int cnt = (int)cur[NBIN - 1];                  // block total after placement
    for (int j = t; j < cnt; j += PTHR) {
        unsigned k = stage[j];
        unsigned bin = k >> BSH;
        unsigned start = cur[bin] - h[bin];
        keysB[tbl_s[bin] + ((unsigned)j - start)] = k;
    }
}

// ---- 13-bit LDS counting sort per coarse bin + run-finish + FINAL edge outputs ----
__global__ __launch_bounds__(512) void k_subsort(const unsigned* __restrict__ src,
                         unsigned* __restrict__ scratch, const unsigned* __restrict__ table,
                         const float2* __restrict__ pos_pool,
                         float* __restrict__ out_erow, float* __restrict__ out_ecol,
                         float* __restrict__ out_valid, float2* __restrict__ out_attr,
                         float* __restrict__ pmax) {
    __shared__ unsigned hist[8192];     // slot(d) = (d&15)*512 + (d>>4)
    __shared__ unsigned stage[SCAP];
    __shared__ float shm[8];
    int b = blockIdx.x, t = threadIdx.x;
    int beg = (int)table[b * GPART];
    int end = (int)table[(b + 1) * GPART];   // b==NBIN-1 -> table[ETBL]==e
    int len = end - beg;
    if (len <= 0) { if (t == 0) pmax[b] = 0.f; return; }
    for (int j = t; j < 8192; j += 512) hist[j] = 0u;
    __syncthreads();
    for (int i = beg + t; i < end; i += 512) {
        unsigned d = (src[i] >> 10) & 8191u;
        atomicAdd(&hist[((d & 15u) << 9) | (d >> 4)], 1u);
    }
    __syncthreads();
    unsigned loc[16];
    unsigned s = 0;
    #pragma unroll
    for (int u = 0; u < 16; ++u) { loc[u] = s; s += hist[u * 512 + t]; }
    unsigned incl = block_incl_scan<512>(s, t);
    bool inlds = (len <= SCAP);
    unsigned base0 = (inlds ? 0u : (unsigned)beg) + incl - s;
    #pragma unroll
    for (int u = 0; u < 16; ++u) hist[u * 512 + t] = base0 + loc[u];
    __syncthreads();
    float am = 0.f;
    if (inlds) {
        for (int i = beg + t; i < end; i += 512) {
            unsigned k = src[i];
            unsigned d = (k >> 10) & 8191u;
            stage[atomicAdd(&hist[((d & 15u) << 9) | (d >> 4)], 1u)] = k;
        }
        __syncthreads();
        // run-finish: runs = equal top-22 bits (never cross bins); sort low 10 bits
        for (int j = t; j < len; j += 512) {
            unsigned hi = stage[j] >> 10;
            if (j > 0 && (stage[j - 1] >> 10) == hi) continue;
            int rend = j + 1;
            while (rend < len && (stage[rend] >> 10) == hi) ++rend;
            for (int a2 = j + 1; a2 < rend; ++a2) {
                unsigned v = stage[a2]; int c = a2 - 1;
                while (c >= j && stage[c] > v) { stage[c + 1] = stage[c]; --c; }
                stage[c + 1] = v;
            }
        }
        __syncthreads();
        for (int j = t; j < len; j += 512) {
            unsigned k = stage[j];
            bool first = (j == 0) || (stage[j - 1] != k);
            unsigned r = k >> 16, c = k & 0xFFFFu;
            bool valid = first && (r != c);
            float ax, ay;
            if (valid) {
                float2 pr = pos_pool[r], pcc = pos_pool[c];
                ax = pr.x - pcc.x; ay = pr.y - pcc.y;
                am = fmaxf(am, fmaxf(fabsf(ax), fabsf(ay)));
            } else {
                ax = __int_as_float(0x7FC00000); ay = 0.f;   // NaN sentinel
            }
            out_erow[beg + j]  = valid ? (float)r : 0.f;
            out_ecol[beg + j]  = valid ? (float)c : 0.f;
            out_valid[beg + j] = valid ? 1.f : 0.f;
            out_attr[beg + j]  = make_float2(ax, ay);
        }
    } else {
        // 27-sigma-unreachable fallback: scatter + run-finish in global scratch
        for (int i = beg + t; i < end; i += 512) {
            unsigned k = src[i];
            unsigned d = (k >> 10) & 8191u;
            scratch[atomicAdd(&hist[((d & 15u) << 9) | (d >> 4)], 1u)] = k;
        }
        __threadfence();
        __syncthreads();
        for (int j = beg + t; j < end; j += 512) {
            unsigned hi = scratch[j] >> 10;
            if (j > beg && (scratch[j - 1] >> 10) == hi) continue;
            int rend = j + 1;
            while (rend < end && (scratch[rend] >> 10) == hi) ++rend;
            for (int a2 = j + 1; a2 < rend; ++a2) {
                unsigned v = scratch[a2]; int c = a2 - 1;
                while (c >= j && scratch[c] > v) { scratch[c + 1] = scratch[c]; --c; }
                scratch[c + 1] = v;
            }
        }
        __threadfence();
        __syncthreads();
        for (int j = beg + t; j < end; j += 512) {
            unsigned k = scratch[j];
            bool first = (j == beg) || (scratch[j - 1] != k);
            unsigned r = k >> 16, c = k & 0xFFFFu;
            bool valid = first && (r != c);
            float ax, ay;
            if (valid) {
                float2 pr = pos_pool[r], pcc = pos_pool[c];
                ax = pr.x - pcc.x; ay = pr.y - pcc.y;
                am = fmaxf(am, fmaxf(fabsf(ax), fabsf(ay)));
            } else {
                ax = __int_as_float(0x7FC00000); ay = 0.f;
            }
            out_erow[j]  = valid ? (float)r : 0.f;
            out_ecol[j]  = valid ? (float)c : 0.f;
            out_valid[j] = valid ? 1.f : 0.f;
            out_attr[j]  = make_float2(ax, ay);
        }
    }
    am = wave_max(am);
    if ((t & 63) == 0) shm[t >> 6] = am;
    __syncthreads();
    if (t == 0) {
        float m = shm[0];
        #pragma unroll
        for (int i2 = 1; i2 < 8; ++i2) m = fmaxf(m, shm[i2]);
        pmax[b] = m;
    }
}

// ---- in-place rescale: attr = cart/(2*max) + 0.5 (NaN sentinel -> 0) ----
__global__ __launch_bounds__(256) void k_rescale(float2* __restrict__ out_attr, int e,
                                                 const float* __restrict__ pmax) {
    __shared__ float shm[4];
    int t = threadIdx.x;
    float m = fmaxf(pmax[t], pmax[t + 256]);
    m = wave_max(m);
    if ((t & 63) == 0) shm[t >> 6] = m;
    __syncthreads();
    float denom = 2.0f * fmaxf(fmaxf(shm[0], shm[1]), fmaxf(shm[2], shm[3]));
    int i = blockIdx.x * blockDim.x + t;
    if (i >= e) return;
    float2 a = out_attr[i];
    bool valid = (a.x == a.x);
    float ax = valid ? a.x / denom + 0.5f : 0.f;
    float ay = valid ? a.y / denom + 0.5f : 0.f;
    out_attr[i] = make_float2(ax, ay);
}

extern "C" void kernel_launch(void* const* d_in, const int* in_sizes, int n_in,
                              void* d_out, int out_size, void* d_ws, size_t ws_size,
                              hipStream_t stream) {
    const float* x    = (const float*)d_in[0];
    const float* pos  = (const float*)d_in[1];
    const int* batch  = (const int*)d_in[2];
    const int* ei     = (const int*)d_in[3];
    const int n = in_sizes[2];
    const int e = in_sizes[3] / 2;

    float* out      = (float*)d_out;
    float* out_x    = out;                                   // [SEG, F]
    float* out_pos  = out_x  + (size_t)SEG * F;              // [SEG, 2]
    float* out_erow = out_pos + (size_t)SEG * 2;             // [E]
    float* out_ecol = out_erow + e;                          // [E]
    float* out_attr = out_ecol + e;                          // [E, 2]
    float* out_val  = out_attr + (size_t)2 * e;              // [E]

    const int nb_e = (e + 255) / 256;

    char* w = (char*)d_ws;
    unsigned* hdr         = (unsigned*)w;                            // 2 u32 (pad 256)
    int*      cl          = (int*)(w + 256);                         // [n]
    int*      node_sorted = (int*)(w + 256 + (size_t)n * 4);         // [n]
    unsigned* node_off    = (unsigned*)(w + 256 + (size_t)n * 8);    // [SEG+1]
    unsigned* table       = node_off + SEG + 1;                      // [ETBL+1] (ntable alias)
    unsigned* keysA       = table + ETBL + 1;                        // [e] (alias: pc)
    unsigned* keysB       = keysA + e;                               // [e] (alias: pn)
    float2*   ppos        = (float2*)(keysB + e);                    // [n]
    unsigned* blksum      = (unsigned*)(ppos + n);                   // [256]
    float2*   pmin        = (float2*)(blksum + 256);                 // [MINB]
    float*    pmax        = (float*)(pmin + MINB);                   // [NBIN]
    unsigned* ntable      = table;                                   // lifetime-disjoint alias
    unsigned* pc          = keysA;
    unsigned* pn          = keysB;

    // node side
    k_min<<<MINB, 256, 0, stream>>>((const float2*)pos, n, pmin);
    k_minred<<<1, 256, 0, stream>>>(pmin, MINB, hdr);
    k_cluster<<<NGP, NTH, 0, stream>>>((const float2*)pos, batch, n, hdr, cl, ntable);
    k_scan1<<<NTBL / 1024, 1024, 0, stream>>>(ntable, ntable, blksum);
    k_scan_add<<<NTBL / 1024, 1024, 0, stream>>>(ntable, blksum, NTBL / 1024, NTBL, (unsigned)n);
    k_npart<<<NGP, NTH, 0, stream>>>(cl, (const float2*)pos, n, ntable, pc, pn, ppos);
    k_ngroup<<<NBIN, 256, 0, stream>>>(pc, pn, ppos, ntable, n, node_off, node_sorted,
                                       (float2*)out_pos);
    k_pool<<<SEG / 4, 256, 0, stream>>>(x, node_sorted, node_off, out_x);
    // edge side
    k_ehist<<<GPART, PTHR, 0, stream>>>(ei, e, cl, keysA, table);
    k_scan1<<<ETBL / 1024, 1024, 0, stream>>>(table, table, blksum);
    k_scan_add<<<ETBL / 1024, 1024, 0, stream>>>(table, blksum, ETBL / 1024, ETBL, (unsigned)e);
    k_partition<<<GPART, PTHR, 0, stream>>>(keysA, e, table, keysB);
    k_subsort<<<NBIN, 512, 0, stream>>>(keysB, keysA, table, (const float2*)out_pos,
                                        out_erow, out_ecol, out_val, (float2*)out_attr, pmax);
    k_rescale<<<nb_e, 256, 0, stream>>>((float2*)out_attr, e, pmax);
}